// Round 14
// baseline (256.203 us; speedup 1.0000x reference)
//
#include <hip/hip_runtime.h>
#include <math.h>

// ---------------------------------------------------------------------------
// ModularSelectCascadeNet forward. B=16384, M=8, NUM_LAYERS=4.
// R14: permuted H column layout (coalesced 8B/lane stores in gemm_mod;
//      perm = within each 64-col group, col j*16+lr stored at lr*4+j;
//      finalize_bn2 + lastWt adjusted with the inverse perm);
//      fused_select/gemm_fsel/gemm_last moved to BM=64 (256 blocks).
// ---------------------------------------------------------------------------

typedef short bf16x8 __attribute__((ext_vector_type(8)));
typedef float f32x4 __attribute__((ext_vector_type(4)));

__device__ __forceinline__ unsigned short f2bf(float f) {
  unsigned u = __float_as_uint(f);
  u += 0x7fffu + ((u >> 16) & 1u);
  return (unsigned short)(u >> 16);
}
__device__ __forceinline__ float bf2f(unsigned short h) {
  return __uint_as_float(((unsigned)h) << 16);
}
__device__ __forceinline__ unsigned pack2(float a, float b) {
  return ((unsigned)f2bf(b) << 16) | f2bf(a);
}
__device__ __forceinline__ void gload_lds16(const void* g, void* l) {
  __builtin_amdgcn_global_load_lds(
      (const __attribute__((address_space(1))) unsigned int*)g,
      (__attribute__((address_space(3))) unsigned int*)l, 16, 0, 0);
}
__device__ __forceinline__ bf16x8 relu_bf8(bf16x8 v) {
  bf16x8 r;
  #pragma unroll
  for (int j = 0; j < 8; ++j) r[j] = v[j] > 0 ? v[j] : (short)0;
  return r;
}

#define EPI_NONE  0
#define EPI_RELU  1
#define EPI_STATS 4

// ---------------------------------------------------------------------------
// Prep: weight transposes + lastW (perm K) + selFt + stats zero. 499 blocks.
__global__ __launch_bounds__(256) void prep_all(
    const float* __restrict__ base_W0, const float* __restrict__ em_W0,
    const float* __restrict__ base_W1, const float* __restrict__ gat_W0,
    const float* __restrict__ gat_W1, const float* __restrict__ sel_W,
    const float* __restrict__ cond_W, const float* __restrict__ last_W,
    const float* __restrict__ selF_W,
    unsigned short* __restrict__ W0t, unsigned short* __restrict__ emW0t,
    unsigned short* __restrict__ W1t, unsigned short* __restrict__ g0t,
    unsigned short* __restrict__ g1t, unsigned short* __restrict__ selWt,
    unsigned short* __restrict__ condWt, unsigned short* __restrict__ lastWt,
    unsigned short* __restrict__ selFt, float* __restrict__ stats)
{
  __shared__ float t[32][33];
  int bid = blockIdx.x;
  const int tid = threadIdx.x;
  const int tx = tid & 31, ty = tid >> 5;

  if (bid < 496) {
    const float* src; unsigned short* dst; int K, N, KP, gx, local;
    if (bid < 64)       { src = base_W0; dst = W0t;   K = 128; N = 400; KP = 128; gx = 4;  local = bid; }
    else if (bid < 128) { src = em_W0;   dst = emW0t; K = 128; N = 400; KP = 128; gx = 4;  local = bid - 64; }
    else if (bid < 232) { src = base_W1; dst = W1t;   K = 400; N = 256; KP = 416; gx = 13; local = bid - 128; }
    else if (bid < 336) { src = gat_W0;  dst = g0t;   K = 400; N = 256; KP = 416; gx = 13; local = bid - 232; }
    else if (bid < 400) { src = gat_W1;  dst = g1t;   K = 256; N = 256; KP = 256; gx = 8;  local = bid - 336; }
    else if (bid < 448) {
      const int i = (bid - 400) / 16;
      src = sel_W + i * 16384; dst = selWt + i * 16384;
      K = 256; N = 64; KP = 256; gx = 8; local = (bid - 400) % 16;
    } else {
      const int i = (bid - 448) / 16;
      src = cond_W + i * 16384; dst = condWt + i * 16384;
      K = 64; N = 256; KP = 64; gx = 2; local = (bid - 448) % 16;
    }
    const int k0 = (local % gx) * 32, n0 = (local / gx) * 32;
    #pragma unroll
    for (int p = 0; p < 4; ++p) {
      const int k = k0 + ty + p * 8;
      t[ty + p * 8][tx] = (k < K && n0 + tx < N) ? src[(size_t)k * N + n0 + tx] : 0.f;
    }
    __syncthreads();
    #pragma unroll
    for (int p = 0; p < 4; ++p) {
      const int n = n0 + ty + p * 8;
      dst[(size_t)n * KP + k0 + tx] = f2bf(t[tx][ty + p * 8]);
    }
    return;
  }
  bid -= 496;

  if (bid == 0) {
    // lastWt with PERMUTED K index: true col tc stored at pk.
    const int tc = tid;                       // 0..255
    const int g = tc >> 6, t64 = tc & 63;
    const int pk = g * 64 + (t64 & 15) * 4 + (t64 >> 4);
    #pragma unroll
    for (int n = 0; n < 18; ++n)
      lastWt[n * 256 + pk] = f2bf(last_W[(size_t)tc * 18 + n]);
    #pragma unroll
    for (int n = 18; n < 64; ++n) lastWt[n * 256 + pk] = 0;
    return;
  }
  bid -= 1;

  if (bid == 0) {  // selFt: [256][8] f32 -> bf16 [16][256] (rows 8..15 zero)
    const int k = tid;
    #pragma unroll
    for (int j = 0; j < 8; ++j) selFt[j * 256 + k] = f2bf(selF_W[k * 8 + j]);
    #pragma unroll
    for (int j = 8; j < 16; ++j) selFt[j * 256 + k] = 0;
    return;
  }

  for (int i = tid; i < 4608; i += 256) stats[i] = 0.f;
}

// ---------------------------------------------------------------------------
// W0 GEMM (fp32 A, converted during reg->LDS staging). grid (4, 128, 2).
__global__ __launch_bounds__(256) void gemm_w0(
    const float* __restrict__ Ax, const float* __restrict__ Ae,
    const unsigned short* __restrict__ Wx, const unsigned short* __restrict__ We,
    const float* __restrict__ bx, const float* __restrict__ be,
    unsigned short* __restrict__ Cx, unsigned short* __restrict__ Ce)
{
  __shared__ unsigned short As[128 * 32];
  __shared__ unsigned short Bs[128 * 32];
  const float* Ap = blockIdx.z ? Ae : Ax;
  const unsigned short* Wp = blockIdx.z ? We : Wx;
  const float* bp = blockIdx.z ? be : bx;
  unsigned short* Cp = blockIdx.z ? Ce : Cx;
  const int row0 = blockIdx.y * 128;
  const int n0 = blockIdx.x * 128;
  const int tid = threadIdx.x;
  const int wid = tid >> 6, lane = tid & 63;
  const int wr = wid >> 1, wc = wid & 1;
  const int arow = tid >> 2, kcol = (tid & 3) * 8;
  const int lr = lane & 15, lk = (lane >> 4) * 8;
  const int lrow = (lane >> 4) * 4;

  f32x4 acc[4][4] = {};
  for (int k0 = 0; k0 < 128; k0 += 32) {
    {
      const float4* s1 = reinterpret_cast<const float4*>(
          Ap + (size_t)(row0 + arow) * 128 + k0 + kcol);
      uint4 w1 = {pack2(s1[0].x, s1[0].y), pack2(s1[0].z, s1[0].w),
                  pack2(s1[1].x, s1[1].y), pack2(s1[1].z, s1[1].w)};
      *reinterpret_cast<uint4*>(&As[arow * 32 + kcol]) = w1;
      const float4* s2 = reinterpret_cast<const float4*>(
          Ap + (size_t)(row0 + 64 + arow) * 128 + k0 + kcol);
      uint4 w2 = {pack2(s2[0].x, s2[0].y), pack2(s2[0].z, s2[0].w),
                  pack2(s2[1].x, s2[1].y), pack2(s2[1].z, s2[1].w)};
      *reinterpret_cast<uint4*>(&As[(64 + arow) * 32 + kcol]) = w2;
    }
    gload_lds16(Wp + (size_t)(n0 + arow) * 128 + k0 + kcol, (char*)Bs + tid * 16);
    gload_lds16(Wp + (size_t)(n0 + 64 + arow) * 128 + k0 + kcol,
                (char*)Bs + 4096 + tid * 16);
    __syncthreads();
    bf16x8 a[4], b[4];
    #pragma unroll
    for (int i = 0; i < 4; ++i)
      a[i] = *reinterpret_cast<const bf16x8*>(&As[(wr * 64 + i * 16 + lr) * 32 + lk]);
    #pragma unroll
    for (int j = 0; j < 4; ++j)
      b[j] = *reinterpret_cast<const bf16x8*>(&Bs[(wc * 64 + j * 16 + lr) * 32 + lk]);
    #pragma unroll
    for (int i = 0; i < 4; ++i)
      #pragma unroll
      for (int j = 0; j < 4; ++j)
        acc[i][j] = __builtin_amdgcn_mfma_f32_16x16x32_bf16(a[i], b[j], acc[i][j], 0, 0, 0);
    __syncthreads();
  }
  #pragma unroll
  for (int j = 0; j < 4; ++j) {
    const int col = n0 + wc * 64 + j * 16 + lr;
    if (col >= 416) continue;
    const bool real = col < 400;
    const float bv = real ? bp[col] : 0.f;
    #pragma unroll
    for (int i = 0; i < 4; ++i) {
      #pragma unroll
      for (int r = 0; r < 4; ++r) {
        const int row = row0 + wr * 64 + i * 16 + lrow + r;
        float v = real ? fmaxf(acc[i][j][r] + bv, 0.f) : 0.f;
        Cp[(size_t)row * 416 + col] = f2bf(v);
      }
    }
  }
}

// ---------------------------------------------------------------------------
// Batched mid GEMM: z=0: out = h1 @ W1t + b1 (raw, bn1 stats);
//                   z=1: si = relu(h1e @ g0t + gb0). BN=64, WM=4, K=416.
__global__ __launch_bounds__(256) void gemm_mid(
    const unsigned short* __restrict__ A0, const unsigned short* __restrict__ W0,
    const float* __restrict__ b0, unsigned short* __restrict__ C0,
    const unsigned short* __restrict__ A1, const unsigned short* __restrict__ W1,
    const float* __restrict__ b1, unsigned short* __restrict__ C1,
    float* __restrict__ sum, float* __restrict__ sumsq)
{
  __shared__ unsigned short As[128 * 32];
  __shared__ unsigned short Bs[64 * 32];
  const bool z1 = blockIdx.z != 0;
  const unsigned short* A = z1 ? A1 : A0;
  const unsigned short* Wt = z1 ? W1 : W0;
  const float* bias = z1 ? b1 : b0;
  unsigned short* C = z1 ? C1 : C0;
  const int row0 = blockIdx.y * 128;
  const int n0 = blockIdx.x * 64;
  const int tid = threadIdx.x;
  const int wid = tid >> 6, lane = tid & 63;
  const int arow = tid >> 2, kcol = (tid & 3) * 8;
  const int lr = lane & 15, lk = (lane >> 4) * 8;
  const int lrow = (lane >> 4) * 4;

  f32x4 acc[2][4] = {};
  for (int k0 = 0; k0 < 416; k0 += 32) {
    gload_lds16(A + (size_t)(row0 + arow) * 416 + k0 + kcol, (char*)As + tid * 16);
    gload_lds16(A + (size_t)(row0 + 64 + arow) * 416 + k0 + kcol, (char*)As + 4096 + tid * 16);
    gload_lds16(Wt + (size_t)(n0 + arow) * 416 + k0 + kcol, (char*)Bs + tid * 16);
    __syncthreads();
    bf16x8 a[2], b[4];
    #pragma unroll
    for (int i = 0; i < 2; ++i)
      a[i] = *reinterpret_cast<const bf16x8*>(&As[(wid * 32 + i * 16 + lr) * 32 + lk]);
    #pragma unroll
    for (int j = 0; j < 4; ++j)
      b[j] = *reinterpret_cast<const bf16x8*>(&Bs[(j * 16 + lr) * 32 + lk]);
    #pragma unroll
    for (int i = 0; i < 2; ++i)
      #pragma unroll
      for (int j = 0; j < 4; ++j)
        acc[i][j] = __builtin_amdgcn_mfma_f32_16x16x32_bf16(a[i], b[j], acc[i][j], 0, 0, 0);
    __syncthreads();
  }
  #pragma unroll
  for (int j = 0; j < 4; ++j) {
    const int col = n0 + j * 16 + lr;
    const float bv = bias[col];
    float s = 0.f, q = 0.f;
    #pragma unroll
    for (int i = 0; i < 2; ++i) {
      #pragma unroll
      for (int r = 0; r < 4; ++r) {
        const int row = row0 + wid * 32 + i * 16 + lrow + r;
        float v = acc[i][j][r] + bv;
        if (z1) v = fmaxf(v, 0.f);
        const unsigned short hv = f2bf(v);
        C[(size_t)row * 256 + col] = hv;
        if (!z1) {
          const float vr = bf2f(hv);
          s += vr;
          q = fmaf(vr, vr, q);
        }
      }
    }
    if (!z1) {
      s += __shfl_xor(s, 16); s += __shfl_xor(s, 32);
      q += __shfl_xor(q, 16); q += __shfl_xor(q, 32);
      if (lane < 16) {
        atomicAdd(&sum[col], s);
        atomicAdd(&sumsq[col], q);
      }
    }
  }
}

// ---------------------------------------------------------------------------
// Generic bf16 MFMA GEMM (used for g1). BM=128, BK=32.
template<int BN, int WM, int WN, int EPI, bool RELU_A>
__global__ __launch_bounds__(256) void gemm_bf16(
    const unsigned short* __restrict__ A, int AS,
    const unsigned short* __restrict__ Wt, const float* __restrict__ bias,
    unsigned short* __restrict__ C, int CS, int Nreal, int NP, int K,
    const unsigned short* __restrict__ emb,
    float* __restrict__ sum, float* __restrict__ sumsq)
{
  constexpr int FRAG_M = 128 / WM / 16;
  constexpr int FRAG_N = BN / WN / 16;
  __shared__ unsigned short As[128 * 32];
  __shared__ unsigned short Bs[BN * 32];
  const int row0 = blockIdx.y * 128;
  const int n0 = blockIdx.x * BN;
  const int tid = threadIdx.x;
  const int wid = tid >> 6, lane = tid & 63;
  const int wr = wid / WN, wc = wid % WN;
  const int arow = tid >> 2;
  const int kcol = (tid & 3) * 8;
  const int lr = lane & 15, lk = (lane >> 4) * 8;
  const int lrow = (lane >> 4) * 4;

  f32x4 acc[FRAG_M][FRAG_N] = {};
  for (int k0 = 0; k0 < K; k0 += 32) {
    gload_lds16(A + (size_t)(row0 + arow) * AS + k0 + kcol, (char*)As + tid * 16);
    gload_lds16(A + (size_t)(row0 + 64 + arow) * AS + k0 + kcol, (char*)As + 4096 + tid * 16);
    gload_lds16(Wt + (size_t)(n0 + arow) * K + k0 + kcol, (char*)Bs + tid * 16);
    if constexpr (BN == 128)
      gload_lds16(Wt + (size_t)(n0 + 64 + arow) * K + k0 + kcol, (char*)Bs + 4096 + tid * 16);
    __syncthreads();
    bf16x8 a[FRAG_M], b[FRAG_N];
    #pragma unroll
    for (int i = 0; i < FRAG_M; ++i) {
      a[i] = *reinterpret_cast<const bf16x8*>(&As[(wr * (128 / WM) + i * 16 + lr) * 32 + lk]);
      if (RELU_A) a[i] = relu_bf8(a[i]);
    }
    #pragma unroll
    for (int j = 0; j < FRAG_N; ++j)
      b[j] = *reinterpret_cast<const bf16x8*>(&Bs[(wc * (BN / WN) + j * 16 + lr) * 32 + lk]);
    #pragma unroll
    for (int i = 0; i < FRAG_M; ++i)
      #pragma unroll
      for (int j = 0; j < FRAG_N; ++j)
        acc[i][j] = __builtin_amdgcn_mfma_f32_16x16x32_bf16(a[i], b[j], acc[i][j], 0, 0, 0);
    __syncthreads();
  }
  #pragma unroll
  for (int j = 0; j < FRAG_N; ++j) {
    const int col = n0 + wc * (BN / WN) + j * 16 + lr;
    if (col >= NP) continue;
    const bool real = col < Nreal;
    const float bv = real ? bias[col] : 0.f;
    float s = 0.f, q = 0.f;
    #pragma unroll
    for (int i = 0; i < FRAG_M; ++i) {
      #pragma unroll
      for (int r = 0; r < 4; ++r) {
        const int row = row0 + wr * (128 / WM) + i * 16 + lrow + r;
        float v = acc[i][j][r] + bv;
        if (EPI == EPI_RELU) v = fmaxf(v, 0.f);
        if (!real) v = 0.f;
        const unsigned short hv = f2bf(v);
        C[(size_t)row * CS + col] = hv;
        if (EPI == EPI_STATS) {
          const float vr = bf2f(hv);
          s += vr;
          q = fmaf(vr, vr, q);
        }
      }
    }
    if (EPI == EPI_STATS) {
      s += __shfl_xor(s, 16); s += __shfl_xor(s, 32);
      q += __shfl_xor(q, 16); q += __shfl_xor(q, 32);
      if (lane < 16) {
        atomicAdd(&sum[col], s);
        atomicAdd(&sumsq[col], q);
      }
    }
  }
}

// ---------------------------------------------------------------------------
// Mod-einsum GEMM (R11 structure + XCD swizzle) with PERMUTED column stores:
// true col j*16+lr stored at position lr*4+j within its 64-col group ->
// each lane stores ushort4 (8B), per-hi-group 128B contiguous. Stats at
// permuted index.
__global__ __launch_bounds__(256) void gemm_mod(
    const unsigned short* __restrict__ A,    // out_bf [16384][256]
    const unsigned short* __restrict__ Wt,   // modWt [2048][256]
    const float* __restrict__ bias, unsigned short* __restrict__ C,
    float* __restrict__ sum, float* __restrict__ sumsq)
{
  __shared__ unsigned short As[128 * 32];
  __shared__ unsigned short Bs[128 * 32];
  const int lin = blockIdx.x;
  const int swz = (lin & 7) * 256 + (lin >> 3);
  const int row0 = (swz >> 4) * 128;
  const int n0 = (swz & 15) * 128;
  const int tid = threadIdx.x;
  const int wid = tid >> 6, lane = tid & 63;
  const int wr = wid >> 1, wc = wid & 1;
  const int arow = tid >> 2;
  const int kcol = (tid & 3) * 8;
  const int lr = lane & 15, lk = (lane >> 4) * 8;
  const int hi = lane >> 4;

  f32x4 acc[4][4] = {};
  for (int k0 = 0; k0 < 256; k0 += 32) {
    gload_lds16(A + (size_t)(row0 + arow) * 256 + k0 + kcol, (char*)As + tid * 16);
    gload_lds16(A + (size_t)(row0 + 64 + arow) * 256 + k0 + kcol, (char*)As + 4096 + tid * 16);
    gload_lds16(Wt + (size_t)(n0 + arow) * 256 + k0 + kcol, (char*)Bs + tid * 16);
    gload_lds16(Wt + (size_t)(n0 + 64 + arow) * 256 + k0 + kcol, (char*)Bs + 4096 + tid * 16);
    __syncthreads();
    bf16x8 a[4], b[4];
    #pragma unroll
    for (int i = 0; i < 4; ++i)
      a[i] = *reinterpret_cast<const bf16x8*>(&As[(wr * 64 + i * 16 + lr) * 32 + lk]);
    #pragma unroll
    for (int j = 0; j < 4; ++j)
      b[j] = *reinterpret_cast<const bf16x8*>(&Bs[(wc * 64 + j * 16 + lr) * 32 + lk]);
    #pragma unroll
    for (int i = 0; i < 4; ++i)
      #pragma unroll
      for (int j = 0; j < 4; ++j)
        acc[i][j] = __builtin_amdgcn_mfma_f32_16x16x32_bf16(a[i], b[j], acc[i][j], 0, 0, 0);
    __syncthreads();
  }

  // bias per j (true col), stats at permuted index
  float bv[4];
  #pragma unroll
  for (int j = 0; j < 4; ++j) bv[j] = bias[n0 + wc * 64 + j * 16 + lr];
  #pragma unroll
  for (int j = 0; j < 4; ++j) {
    float s = 0.f, q = 0.f;
    #pragma unroll
    for (int i = 0; i < 4; ++i)
      #pragma unroll
      for (int r = 0; r < 4; ++r) {
        const float vr = bf2f(f2bf(acc[i][j][r] + bv[j]));
        s += vr;
        q = fmaf(vr, vr, q);
      }
    s += __shfl_xor(s, 16); s += __shfl_xor(s, 32);
    q += __shfl_xor(q, 16); q += __shfl_xor(q, 32);
    if (lane < 16) {
      const int pcol = n0 + wc * 64 + lr * 4 + j;  // lr == lane here
      atomicAdd(&sum[pcol], s);
      atomicAdd(&sumsq[pcol], q);
    }
  }
  // coalesced permuted stores: lane writes ushort4 at pbase
  const int pbase = n0 + wc * 64 + lr * 4;
  #pragma unroll
  for (int i = 0; i < 4; ++i) {
    #pragma unroll
    for (int r = 0; r < 4; ++r) {
      const int row = row0 + wr * 64 + i * 16 + hi * 4 + r;
      ushort4 o;
      o.x = f2bf(acc[i][0][r] + bv[0]);
      o.y = f2bf(acc[i][1][r] + bv[1]);
      o.z = f2bf(acc[i][2][r] + bv[2]);
      o.w = f2bf(acc[i][3][r] + bv[3]);
      *reinterpret_cast<ushort4*>(&C[(size_t)row * 2048 + pbase]) = o;
    }
  }
}

// ---------------------------------------------------------------------------
// Fused select iteration, BM=64 (256 blocks).
template<bool RELU_A>
__global__ __launch_bounds__(256) void fused_select(
    const unsigned short* __restrict__ A, const unsigned short* __restrict__ selWt,
    const float* __restrict__ selb, const unsigned short* __restrict__ condWt,
    const float* __restrict__ condb, const unsigned short* __restrict__ emb,
    const float* __restrict__ u, int u_off,
    float* __restrict__ gs, unsigned short* __restrict__ siout)
{
  __shared__ unsigned short As[64 * 32];    // 4 KB
  __shared__ unsigned short Bs[64 * 32];    // 4 KB
  __shared__ unsigned short Ls[64 * 72];    // 9.2 KB logits (pad 72)
  const int tid = threadIdx.x;
  const int wid = tid >> 6, lane = tid & 63;
  const int lr = lane & 15, hi = lane >> 4;
  const int lk = hi * 8;
  const int row0 = blockIdx.x * 64;
  const int arow = tid >> 2, kcol = (tid & 3) * 8;

  // ---- phase 1: sel GEMM (64 rows x 64 cols, K=256); wave owns 16 rows ----
  {
    f32x4 acc[4] = {};
    for (int k0 = 0; k0 < 256; k0 += 32) {
      gload_lds16(A + (size_t)(row0 + arow) * 256 + k0 + kcol, (char*)As + tid * 16);
      gload_lds16(selWt + (size_t)arow * 256 + k0 + kcol, (char*)Bs + tid * 16);
      __syncthreads();
      bf16x8 a = *reinterpret_cast<const bf16x8*>(&As[(wid * 16 + lr) * 32 + lk]);
      if (RELU_A) a = relu_bf8(a);
      #pragma unroll
      for (int j = 0; j < 4; ++j) {
        const bf16x8 b = *reinterpret_cast<const bf16x8*>(&Bs[(j * 16 + lr) * 32 + lk]);
        acc[j] = __builtin_amdgcn_mfma_f32_16x16x32_bf16(a, b, acc[j], 0, 0, 0);
      }
      __syncthreads();
    }
    #pragma unroll
    for (int j = 0; j < 4; ++j) {
      const int col = j * 16 + lr;
      const float bv = selb[col];
      #pragma unroll
      for (int r = 0; r < 4; ++r) {
        const int row = wid * 16 + hi * 4 + r;
        Ls[row * 72 + col] = f2bf(tanhf(acc[j][r] + bv));
      }
    }
  }
  __syncthreads();

  // ---- phase 2: gumbel softmax (512 (b,m) pairs, 2 per thread) ----
  #pragma unroll
  for (int p = 0; p < 2; ++p) {
    const int pair = p * 256 + tid;
    const int bl = pair >> 3, mm = pair & 7;
    const int bg = row0 + bl;
    float v[8];
    #pragma unroll
    for (int jj = 0; jj < 8; ++jj) v[jj] = bf2f(Ls[bl * 72 + mm * 8 + jj]);
    const float* up = u + (size_t)bg * 192 + u_off + mm * 8;
    #pragma unroll
    for (int jj = 0; jj < 8; ++jj) {
      const float uu = fminf(fmaxf(up[jj], 1e-10f), 0.9999999f);
      v[jj] -= logf(-logf(uu));
    }
    float mx = v[0];
    #pragma unroll
    for (int jj = 1; jj < 8; ++jj) mx = fmaxf(mx, v[jj]);
    float s = 0.f;
    #pragma unroll
    for (int jj = 0; jj < 8; ++jj) { v[jj] = expf(v[jj] - mx); s += v[jj]; }
    const float inv = 1.f / s;
    float* op = gs + (size_t)bg * 64 + mm * 8;
    #pragma unroll
    for (int jj = 0; jj < 8; ++jj) op[jj] = v[jj] * inv;
  }

  // ---- phase 3: cond GEMM (64 rows x 256 cols, K=64); waves 2x2 ----
  {
    const int wr2 = wid >> 1, wc2 = wid & 1;
    f32x4 acc2[2][8] = {};
    #pragma unroll
    for (int kq = 0; kq < 2; ++kq) {
      const int k0 = kq * 32;
      bf16x8 a2[2];
      #pragma unroll
      for (int i = 0; i < 2; ++i)
        a2[i] = *reinterpret_cast<const bf16x8*>(
            &Ls[(wr2 * 32 + i * 16 + lr) * 72 + k0 + hi * 8]);
      #pragma unroll
      for (int j = 0; j < 8; ++j) {
        const bf16x8 b2 = *reinterpret_cast<const bf16x8*>(
            condWt + (size_t)(wc2 * 128 + j * 16 + lr) * 64 + k0 + hi * 8);
        #pragma unroll
        for (int i = 0; i < 2; ++i)
          acc2[i][j] = __builtin_amdgcn_mfma_f32_16x16x32_bf16(a2[i], b2, acc2[i][j], 0, 0, 0);
      }
    }
    #pragma unroll
    for (int j = 0; j < 8; ++j) {
      const int col = wc2 * 128 + j * 16 + lr;
      const float bv = condb[col];
      #pragma unroll
      for (int i = 0; i < 2; ++i)
        #pragma unroll
        for (int r = 0; r < 4; ++r) {
          const int row = row0 + wr2 * 32 + i * 16 + hi * 4 + r;
          float vv = (acc2[i][j][r] + bv) * bf2f(emb[(size_t)row * 256 + col]);
          siout[(size_t)row * 256 + col] = f2bf(fmaxf(vv, 0.f));
        }
    }
  }
}

// ---------------------------------------------------------------------------
// Final select: MFMA GEMM (BM=64, K=256, 8 real cols) + gumbel epilogue.
// grid 256.
__global__ __launch_bounds__(256) void gemm_fsel(
    const unsigned short* __restrict__ A, const unsigned short* __restrict__ Wt,
    const float* __restrict__ bias, const float* __restrict__ u,
    float* __restrict__ fs)
{
  __shared__ unsigned short As[64 * 32];
  __shared__ unsigned short Bs[16 * 32];
  const int row0 = blockIdx.x * 64;
  const int tid = threadIdx.x;
  const int wid = tid >> 6, lane = tid & 63;
  const int arow = tid >> 2, kcol = (tid & 3) * 8;
  const int lr = lane & 15, hi = lane >> 4;
  const int lk = hi * 8;

  f32x4 acc = {};
  for (int k0 = 0; k0 < 256; k0 += 32) {
    gload_lds16(A + (size_t)(row0 + arow) * 256 + k0 + kcol, (char*)As + tid * 16);
    if (wid == 0)
      gload_lds16(Wt + (size_t)(lane >> 2) * 256 + k0 + (lane & 3) * 8, (char*)Bs + lane * 16);
    __syncthreads();
    const bf16x8 a = *reinterpret_cast<const bf16x8*>(&As[(wid * 16 + lr) * 32 + lk]);
    const bf16x8 b = *reinterpret_cast<const bf16x8*>(&Bs[lr * 32 + lk]);
    acc = __builtin_amdgcn_mfma_f32_16x16x32_bf16(a, b, acc, 0, 0, 0);
    __syncthreads();
  }
  const float bv = (lr < 8) ? bias[lr] : 0.f;
  #pragma unroll
  for (int r = 0; r < 4; ++r) {
    const int row = row0 + wid * 16 + hi * 4 + r;
    float v = acc[r] + bv;
    if (lr < 8) {
      const float uu = fminf(fmaxf(u[(size_t)row * 8 + lr], 1e-10f), 0.9999999f);
      v -= logf(-logf(uu));
    }
    float mx = v;
    mx = fmaxf(mx, __shfl_xor(mx, 1));
    mx = fmaxf(mx, __shfl_xor(mx, 2));
    mx = fmaxf(mx, __shfl_xor(mx, 4));
    const float e = expf(v - mx);
    float ssum = e;
    ssum += __shfl_xor(ssum, 1);
    ssum += __shfl_xor(ssum, 2);
    ssum += __shfl_xor(ssum, 4);
    if (lr < 8) fs[(size_t)row * 8 + lr] = e / ssum;
  }
}

// ---------------------------------------------------------------------------
// Fold mod weights with inline bn1 finalize. grid (8, 8, 9).
__global__ __launch_bounds__(256) void fold_modw_all(
    const float* __restrict__ W, const float* __restrict__ g1,
    const float* __restrict__ b1, const float* __restrict__ modb,
    const float* __restrict__ sum1, const float* __restrict__ sumsq1,
    unsigned short* __restrict__ Wt, float* __restrict__ bias2)
{
  const float invB = 1.f / 16384.f;
  if (blockIdx.z == 8) {
    if (blockIdx.y != 0) return;
    const int m = blockIdx.x, h = threadIdx.x;
    float acc = modb[m * 256 + h];
    for (int d = 0; d < 256; ++d) {
      const float mean = sum1[d] * invB;
      const float var = sumsq1[d] * invB - mean * mean;
      const float r = rsqrtf(var + 1e-5f);
      const float c = b1[m * 256 + d] - mean * r * g1[m * 256 + d];
      acc = fmaf(c, W[((size_t)m * 256 + d) * 256 + h], acc);
    }
    bias2[m * 256 + h] = acc;
    return;
  }
  __shared__ float t[32][33];
  const int m = blockIdx.z, d0 = blockIdx.y * 32, h0 = blockIdx.x * 32;
  const int tx = threadIdx.x & 31, ty = threadIdx.x >> 5;
  #pragma unroll
  for (int p = 0; p < 4; ++p) {
    const int d = d0 + ty + p * 8;
    const float mean = sum1[d] * invB;
    const float var = sumsq1[d] * invB - mean * mean;
    const float r = rsqrtf(var + 1e-5f);
    t[ty + p * 8][tx] = W[((size_t)m * 256 + d) * 256 + h0 + tx] * r * g1[m * 256 + d];
  }
  __syncthreads();
  #pragma unroll
  for (int p = 0; p < 4; ++p) {
    const int h = h0 + ty + p * 8;
    Wt[((size_t)m * 256 + h) * 256 + d0 + tx] = f2bf(t[tx][ty + p * 8]);
  }
}

// bn2 finalize over PERMUTED column space: g/b fetched at inverse-perm col.
__global__ void finalize_bn2(const float* __restrict__ sum, const float* __restrict__ sumsq,
                             const float* __restrict__ g, const float* __restrict__ b,
                             float* __restrict__ scale, float* __restrict__ shift)
{
  const int i = blockIdx.x * 256 + threadIdx.x;   // permuted index, 0..2047
  const int pos64 = i & 63;
  const int tc = (i & ~63) | ((pos64 & 3) * 16 + (pos64 >> 2));  // true col
  const float invB = 1.f / 16384.f;
  const float m = sum[i] * invB;
  const float v = sumsq[i] * invB - m * m;
  const float r = rsqrtf(v + 1e-5f);
  const float sc = r * g[tc];
  scale[i] = sc;
  shift[i] = b[tc] - m * sc;
}

// ---------------------------------------------------------------------------
// Cascade (R5-proven; operates transparently on permuted column positions).
__global__ __launch_bounds__(256) void final_cascade(
    const unsigned short* __restrict__ H, const float* __restrict__ scale2,
    const float* __restrict__ shift2, const float* __restrict__ gs0,
    const float* __restrict__ gs1, const float* __restrict__ gs2,
    const float* __restrict__ fs, unsigned short* __restrict__ ovec)
{
  const int wave = threadIdx.x >> 6, lane = threadIdx.x & 63;
  const int b = __builtin_amdgcn_readfirstlane(blockIdx.x * 4 + wave);
  const int c0 = lane << 2;

  float prev[8][4];
  #pragma unroll
  for (int m = 0; m < 8; ++m) {
    const int gc = m * 256 + c0;
    const ushort4 h = *reinterpret_cast<const ushort4*>(&H[(size_t)b * 2048 + gc]);
    const float4 sc = *reinterpret_cast<const float4*>(&scale2[gc]);
    const float4 sh = *reinterpret_cast<const float4*>(&shift2[gc]);
    prev[m][0] = bf2f(h.x) * sc.x + sh.x;
    prev[m][1] = bf2f(h.y) * sc.y + sh.y;
    prev[m][2] = bf2f(h.z) * sc.z + sh.z;
    prev[m][3] = bf2f(h.w) * sc.w + sh.w;
  }

  const float* sel0 = gs2 + (size_t)b * 64;
  const float* sel1 = gs1 + (size_t)b * 64;
  const float* sel2 = gs0 + (size_t)b * 64;
  #pragma unroll
  for (int l = 0; l < 3; ++l) {
    const float* sp = (l == 0) ? sel0 : (l == 1) ? sel1 : sel2;
    float nw[8][4];
    #pragma unroll
    for (int m = 0; m < 8; ++m) {
      float a0 = 0.f, a1 = 0.f, a2 = 0.f, a3 = 0.f;
      #pragma unroll
      for (int k = 0; k < 8; ++k) {
        const float s = sp[m * 8 + k];
        a0 = fmaf(s, prev[k][0], a0);
        a1 = fmaf(s, prev[k][1], a1);
        a2 = fmaf(s, prev[k][2], a2);
        a3 = fmaf(s, prev[k][3], a3);
      }
      nw[m][0] = fmaxf(a0, 0.f); nw[m][1] = fmaxf(a1, 0.f);
      nw[m][2] = fmaxf(a2, 0.f); nw[m][3] = fmaxf(a3, 0.f);
    }
    #pragma unroll
    for (int m = 0; m < 8; ++m)
      #pragma unroll
      for (int c = 0; c < 4; ++c)
        prev[m][c] = nw[m][c];
  }

  const float* fp = fs + (size_t)b * 8;
  float ov[4] = {0.f, 0.f, 0.f, 0.f};
  #pragma unroll
  for (int m = 0; m < 8; ++m) {
    const float s = fp[m];
    ov[0] = fmaf(s, prev[m][0], ov[0]);
    ov[1] = fmaf(s, prev[m][1], ov[1]);
    ov[2] = fmaf(s, prev[m][2], ov[2]);
    ov[3] = fmaf(s, prev[m][3], ov[3]);
  }
  ushort4 o;
  o.x = f2bf(ov[0]); o.y = f2bf(ov[1]); o.z = f2bf(ov[2]); o.w = f2bf(ov[3]);
  *reinterpret_cast<ushort4*>(&ovec[(size_t)b * 256 + c0]) = o;
}

// ---------------------------------------------------------------------------
// Last GEMM (BM=64, grid 256): out = ovec(perm) @ lastWt(perm K)^T + lastb.
__global__ __launch_bounds__(256) void gemm_last(
    const unsigned short* __restrict__ A, const unsigned short* __restrict__ Wt,
    const float* __restrict__ bias, float* __restrict__ out)
{
  __shared__ unsigned short As[64 * 32];
  __shared__ unsigned short Bs[64 * 32];
  const int row0 = blockIdx.x * 64;
  const int tid = threadIdx.x;
  const int wid = tid >> 6, lane = tid & 63;
  const int arow = tid >> 2, kcol = (tid & 3) * 8;
  const int lr = lane & 15, hi = lane >> 4;
  const int lk = hi * 8;

  f32x4 acc[4] = {};
  for (int k0 = 0; k0 < 256; k0 += 32) {
    gload_lds16(A + (size_t)(row0 + arow) * 256 + k0 + kcol, (char*)As + tid * 16);
    gload_lds16(Wt + (size_t)arow * 256 + k0 + kcol, (char*)Bs + tid * 16);
    __syncthreads();
    const bf16x8 a = *reinterpret_cast<const bf16x8*>(&As[(wid * 16 + lr) * 32 + lk]);
    #pragma unroll
    for (int j = 0; j < 4; ++j) {
      const bf16x8 b = *reinterpret_cast<const bf16x8*>(&Bs[(j * 16 + lr) * 32 + lk]);
      acc[j] = __builtin_amdgcn_mfma_f32_16x16x32_bf16(a, b, acc[j], 0, 0, 0);
    }
    __syncthreads();
  }
  #pragma unroll
  for (int j = 0; j < 2; ++j) {
    const int col = j * 16 + lr;
    if (col >= 18) continue;
    const float bv = bias[col];
    #pragma unroll
    for (int r = 0; r < 4; ++r) {
      const int row = row0 + wid * 16 + hi * 4 + r;
      out[(size_t)row * 18 + col] = acc[j][r] + bv;
    }
  }
}

extern "C" void kernel_launch(void* const* d_in, const int* in_sizes, int n_in,
                              void* d_out, int out_size, void* d_ws, size_t ws_size,
                              hipStream_t stream)
{
  (void)in_sizes; (void)n_in; (void)out_size; (void)ws_size;
  const float* x       = (const float*)d_in[0];
  const float* embi    = (const float*)d_in[1];
  const float* u_sel   = (const float*)d_in[2];
  const float* u_fin   = (const float*)d_in[3];
  const float* base_W0 = (const float*)d_in[4];
  const float* base_b0 = (const float*)d_in[5];
  const float* base_W1 = (const float*)d_in[6];
  const float* base_b1 = (const float*)d_in[7];
  const float* em_W0   = (const float*)d_in[8];
  const float* em_b0   = (const float*)d_in[9];
  const float* gat_W0  = (const float*)d_in[10];
  const float* gat_b0  = (const float*)d_in[11];
  const float* gat_W1  = (const float*)d_in[12];
  const float* gat_b1  = (const float*)d_in[13];
  const float* sel_W   = (const float*)d_in[14];
  const float* sel_b   = (const float*)d_in[15];
  const float* selF_W  = (const float*)d_in[16];
  const float* selF_b  = (const float*)d_in[17];
  const float* cond_W  = (const float*)d_in[18];
  const float* cond_b  = (const float*)d_in[19];
  const float* mod_W   = (const float*)d_in[20];
  const float* mod_b   = (const float*)d_in[21];
  const float* last_W  = (const float*)d_in[22];
  const float* last_b  = (const float*)d_in[23];
  const float* bn1_g   = (const float*)d_in[24];
  const float* bn1_b   = (const float*)d_in[25];
  const float* bn2_g   = (const float*)d_in[26];
  const float* bn2_b   = (const float*)d_in[27];

  // --- workspace layout (byte offsets) ---
  char* WSB = (char*)d_ws;
  unsigned short* h_big    = (unsigned short*)(WSB + 0);          // 16384x2048 bf16
  unsigned short* h1e      = (unsigned short*)(WSB + 67108864);   // 16384x416 (em)
  unsigned short* ovec_bf  = (unsigned short*)(WSB + 67108864);   // overlaps dead h1e
  unsigned short* h1       = (unsigned short*)(WSB + 81000448);   // 16384x416 (base)
  unsigned short* emb_bf   = (unsigned short*)(WSB + 103020544);  // 16384x256
  unsigned short* si_bf    = (unsigned short*)(WSB + 111409152);  // 16384x256
  unsigned short* out_bf   = (unsigned short*)(WSB + 119797760);  // 16384x256
  float* gs0   = (float*)(WSB + 130283520);  // 16384x64
  float* gs1   = (float*)(WSB + 134477824);
  float* gs2   = (float*)(WSB + 138672128);
  float* bufFs = (float*)(WSB + 142866432);  // 16384x8
  unsigned short* W0t   = (unsigned short*)(WSB + 143390720);  // 512x128
  unsigned short* emW0t = (unsigned short*)(WSB + 143521792);  // 512x128
  unsigned short* W1t   = (unsigned short*)(WSB + 143652864);  // 256x416
  unsigned short* g0t   = (unsigned short*)(WSB + 143865856);  // 256x416
  unsigned short* g1t   = (unsigned short*)(WSB + 144078848);  // 256x256
  unsigned short* selWt = (unsigned short*)(WSB + 144209920);  // 3x64x256
  unsigned short* condWt= (unsigned short*)(WSB + 144308224);  // 3x256x64
  unsigned short* modWt = (unsigned short*)(WSB + 144406528);  // 8x256x256
  float* bias2  = (float*)(WSB + 146503680);  // 2048
  float* stats  = (float*)(WSB + 146511872);  // 4608 floats
  unsigned short* lastWt = (unsigned short*)(WSB + 146530304); // 64x256 bf16
  float* scale2 = (float*)(WSB + 146563072);  // 2048
  float* shift2 = (float*)(WSB + 146571264);  // 2048
  unsigned short* selFt = (unsigned short*)(WSB + 146579456);  // 16x256 bf16
  float* sum1   = stats;        float* sumsq1 = stats + 256;
  float* sum2   = stats + 512;  float* sumsq2 = stats + 2560;

  const dim3 blk(256);
  // prep (weight transposes + lastWt perm + selFt + stats zero)
  prep_all<<<dim3(499), blk, 0, stream>>>(
      base_W0, em_W0, base_W1, gat_W0, gat_W1, sel_W, cond_W, last_W, selF_W,
      W0t, emW0t, W1t, g0t, g1t, selWt, condWt, lastWt, selFt, stats);

  // batched W0 GEMMs from fp32 inputs
  gemm_w0<<<dim3(4, 128, 2), blk, 0, stream>>>(
      x, embi, W0t, emW0t, base_b0, em_b0, h1, h1e);
  // batched mid GEMMs: z=0 W1->out (bn1 stats), z=1 g0->si (relu)
  gemm_mid<<<dim3(4, 128, 2), blk, 0, stream>>>(
      h1, W1t, base_b1, out_bf, h1e, g0t, gat_b0, si_bf, sum1, sumsq1);
  // g1 -> emb
  gemm_bf16<64, 4, 1, EPI_NONE, false><<<dim3(4, 128), blk, 0, stream>>>(
      si_bf, 256, g1t, gat_b1, emb_bf, 256, 256, 256, 256, nullptr, nullptr, nullptr);
  // fused select loop (BM=64, 256 blocks)
  fused_select<true><<<dim3(256), blk, 0, stream>>>(
      emb_bf, selWt, sel_b, condWt, cond_b, emb_bf, u_sel, 0, gs0, si_bf);
  fused_select<false><<<dim3(256), blk, 0, stream>>>(
      si_bf, selWt + 16384, sel_b + 64, condWt + 16384, cond_b + 256, emb_bf,
      u_sel, 64, gs1, si_bf);
  fused_select<false><<<dim3(256), blk, 0, stream>>>(
      si_bf, selWt + 32768, sel_b + 128, condWt + 32768, cond_b + 512, emb_bf,
      u_sel, 128, gs2, si_bf);
  // final select (MFMA, 256 blocks)
  gemm_fsel<<<dim3(256), blk, 0, stream>>>(si_bf, selFt, selF_b, u_fin, bufFs);
  // bn1 finalize + mod weight fold + bias2
  fold_modw_all<<<dim3(8, 8, 9), blk, 0, stream>>>(
      mod_W, bn1_g, bn1_b, mod_b, sum1, sumsq1, modWt, bias2);
  // mod einsum -> h_big (permuted col layout, fused bn2 stats)
  gemm_mod<<<dim3(2048), blk, 0, stream>>>(out_bf, modWt, bias2, h_big, sum2, sumsq2);
  finalize_bn2<<<dim3(8), blk, 0, stream>>>(sum2, sumsq2, bn2_g, bn2_b, scale2, shift2);
  // cascade -> ovec (permuted), then last GEMM (perm lastWt) -> d_out
  final_cascade<<<dim3(4096), blk, 0, stream>>>(
      h_big, scale2, shift2, gs0, gs1, gs2, bufFs, ovec_bf);
  gemm_last<<<dim3(256), blk, 0, stream>>>(ovec_bf, lastWt, last_b, (float*)d_out);
}

// Round 15
// 247.658 us; speedup vs baseline: 1.0345x; 1.0345x over previous
//
#include <hip/hip_runtime.h>
#include <math.h>

// ---------------------------------------------------------------------------
// ModularSelectCascadeNet forward. B=16384, M=8, NUM_LAYERS=4.
// R15 == R13 (best measured: 248.1 µs). R14's permuted-store + BM=64 variants
// regressed (double-quantize epilogue; write coalescing not on critical path).
// ---------------------------------------------------------------------------

typedef short bf16x8 __attribute__((ext_vector_type(8)));
typedef float f32x4 __attribute__((ext_vector_type(4)));

__device__ __forceinline__ unsigned short f2bf(float f) {
  unsigned u = __float_as_uint(f);
  u += 0x7fffu + ((u >> 16) & 1u);
  return (unsigned short)(u >> 16);
}
__device__ __forceinline__ float bf2f(unsigned short h) {
  return __uint_as_float(((unsigned)h) << 16);
}
__device__ __forceinline__ unsigned pack2(float a, float b) {
  return ((unsigned)f2bf(b) << 16) | f2bf(a);
}
__device__ __forceinline__ void gload_lds16(const void* g, void* l) {
  __builtin_amdgcn_global_load_lds(
      (const __attribute__((address_space(1))) unsigned int*)g,
      (__attribute__((address_space(3))) unsigned int*)l, 16, 0, 0);
}
__device__ __forceinline__ bf16x8 relu_bf8(bf16x8 v) {
  bf16x8 r;
  #pragma unroll
  for (int j = 0; j < 8; ++j) r[j] = v[j] > 0 ? v[j] : (short)0;
  return r;
}

#define EPI_NONE  0
#define EPI_RELU  1
#define EPI_STATS 4

// ---------------------------------------------------------------------------
// Prep: weight transposes + lastW + selFt + stats zero. 506 blocks.
__global__ __launch_bounds__(256) void prep_all(
    const float* __restrict__ base_W0, const float* __restrict__ em_W0,
    const float* __restrict__ base_W1, const float* __restrict__ gat_W0,
    const float* __restrict__ gat_W1, const float* __restrict__ sel_W,
    const float* __restrict__ cond_W, const float* __restrict__ last_W,
    const float* __restrict__ selF_W,
    unsigned short* __restrict__ W0t, unsigned short* __restrict__ emW0t,
    unsigned short* __restrict__ W1t, unsigned short* __restrict__ g0t,
    unsigned short* __restrict__ g1t, unsigned short* __restrict__ selWt,
    unsigned short* __restrict__ condWt, unsigned short* __restrict__ lastWt,
    unsigned short* __restrict__ selFt, float* __restrict__ stats)
{
  __shared__ float t[32][33];
  int bid = blockIdx.x;
  const int tid = threadIdx.x;
  const int tx = tid & 31, ty = tid >> 5;

  if (bid < 496) {
    const float* src; unsigned short* dst; int K, N, KP, gx, local;
    if (bid < 64)       { src = base_W0; dst = W0t;   K = 128; N = 400; KP = 128; gx = 4;  local = bid; }
    else if (bid < 128) { src = em_W0;   dst = emW0t; K = 128; N = 400; KP = 128; gx = 4;  local = bid - 64; }
    else if (bid < 232) { src = base_W1; dst = W1t;   K = 400; N = 256; KP = 416; gx = 13; local = bid - 128; }
    else if (bid < 336) { src = gat_W0;  dst = g0t;   K = 400; N = 256; KP = 416; gx = 13; local = bid - 232; }
    else if (bid < 400) { src = gat_W1;  dst = g1t;   K = 256; N = 256; KP = 256; gx = 8;  local = bid - 336; }
    else if (bid < 448) {
      const int i = (bid - 400) / 16;
      src = sel_W + i * 16384; dst = selWt + i * 16384;
      K = 256; N = 64; KP = 256; gx = 8; local = (bid - 400) % 16;
    } else {
      const int i = (bid - 448) / 16;
      src = cond_W + i * 16384; dst = condWt + i * 16384;
      K = 64; N = 256; KP = 64; gx = 2; local = (bid - 448) % 16;
    }
    const int k0 = (local % gx) * 32, n0 = (local / gx) * 32;
    #pragma unroll
    for (int p = 0; p < 4; ++p) {
      const int k = k0 + ty + p * 8;
      t[ty + p * 8][tx] = (k < K && n0 + tx < N) ? src[(size_t)k * N + n0 + tx] : 0.f;
    }
    __syncthreads();
    #pragma unroll
    for (int p = 0; p < 4; ++p) {
      const int n = n0 + ty + p * 8;
      dst[(size_t)n * KP + k0 + tx] = f2bf(t[tx][ty + p * 8]);
    }
    return;
  }
  bid -= 496;

  if (bid < 8) {
    const int k0 = bid * 32;
    #pragma unroll
    for (int p = 0; p < 4; ++p)
      t[ty + p * 8][tx] = (tx < 18) ? last_W[(size_t)(k0 + ty + p * 8) * 18 + tx] : 0.f;
    __syncthreads();
    #pragma unroll
    for (int p = 0; p < 4; ++p) {
      const int n = ty + p * 8;
      lastWt[(size_t)n * 256 + k0 + tx] = f2bf(t[tx][n]);
      lastWt[(size_t)(n + 32) * 256 + k0 + tx] = 0;
    }
    return;
  }
  bid -= 8;

  if (bid == 0) {  // selFt: [256][8] f32 -> bf16 [16][256] (rows 8..15 zero)
    const int k = tid;
    #pragma unroll
    for (int j = 0; j < 8; ++j) selFt[j * 256 + k] = f2bf(selF_W[k * 8 + j]);
    #pragma unroll
    for (int j = 8; j < 16; ++j) selFt[j * 256 + k] = 0;
    return;
  }

  for (int i = tid; i < 4608; i += 256) stats[i] = 0.f;
}

// ---------------------------------------------------------------------------
// W0 GEMM (fp32 A, converted during reg->LDS staging). grid (4, 128, 2).
__global__ __launch_bounds__(256) void gemm_w0(
    const float* __restrict__ Ax, const float* __restrict__ Ae,
    const unsigned short* __restrict__ Wx, const unsigned short* __restrict__ We,
    const float* __restrict__ bx, const float* __restrict__ be,
    unsigned short* __restrict__ Cx, unsigned short* __restrict__ Ce)
{
  __shared__ unsigned short As[128 * 32];
  __shared__ unsigned short Bs[128 * 32];
  const float* Ap = blockIdx.z ? Ae : Ax;
  const unsigned short* Wp = blockIdx.z ? We : Wx;
  const float* bp = blockIdx.z ? be : bx;
  unsigned short* Cp = blockIdx.z ? Ce : Cx;
  const int row0 = blockIdx.y * 128;
  const int n0 = blockIdx.x * 128;
  const int tid = threadIdx.x;
  const int wid = tid >> 6, lane = tid & 63;
  const int wr = wid >> 1, wc = wid & 1;
  const int arow = tid >> 2, kcol = (tid & 3) * 8;
  const int lr = lane & 15, lk = (lane >> 4) * 8;
  const int lrow = (lane >> 4) * 4;

  f32x4 acc[4][4] = {};
  for (int k0 = 0; k0 < 128; k0 += 32) {
    {
      const float4* s1 = reinterpret_cast<const float4*>(
          Ap + (size_t)(row0 + arow) * 128 + k0 + kcol);
      uint4 w1 = {pack2(s1[0].x, s1[0].y), pack2(s1[0].z, s1[0].w),
                  pack2(s1[1].x, s1[1].y), pack2(s1[1].z, s1[1].w)};
      *reinterpret_cast<uint4*>(&As[arow * 32 + kcol]) = w1;
      const float4* s2 = reinterpret_cast<const float4*>(
          Ap + (size_t)(row0 + 64 + arow) * 128 + k0 + kcol);
      uint4 w2 = {pack2(s2[0].x, s2[0].y), pack2(s2[0].z, s2[0].w),
                  pack2(s2[1].x, s2[1].y), pack2(s2[1].z, s2[1].w)};
      *reinterpret_cast<uint4*>(&As[(64 + arow) * 32 + kcol]) = w2;
    }
    gload_lds16(Wp + (size_t)(n0 + arow) * 128 + k0 + kcol, (char*)Bs + tid * 16);
    gload_lds16(Wp + (size_t)(n0 + 64 + arow) * 128 + k0 + kcol,
                (char*)Bs + 4096 + tid * 16);
    __syncthreads();
    bf16x8 a[4], b[4];
    #pragma unroll
    for (int i = 0; i < 4; ++i)
      a[i] = *reinterpret_cast<const bf16x8*>(&As[(wr * 64 + i * 16 + lr) * 32 + lk]);
    #pragma unroll
    for (int j = 0; j < 4; ++j)
      b[j] = *reinterpret_cast<const bf16x8*>(&Bs[(wc * 64 + j * 16 + lr) * 32 + lk]);
    #pragma unroll
    for (int i = 0; i < 4; ++i)
      #pragma unroll
      for (int j = 0; j < 4; ++j)
        acc[i][j] = __builtin_amdgcn_mfma_f32_16x16x32_bf16(a[i], b[j], acc[i][j], 0, 0, 0);
    __syncthreads();
  }
  #pragma unroll
  for (int j = 0; j < 4; ++j) {
    const int col = n0 + wc * 64 + j * 16 + lr;
    if (col >= 416) continue;
    const bool real = col < 400;
    const float bv = real ? bp[col] : 0.f;
    #pragma unroll
    for (int i = 0; i < 4; ++i) {
      #pragma unroll
      for (int r = 0; r < 4; ++r) {
        const int row = row0 + wr * 64 + i * 16 + lrow + r;
        float v = real ? fmaxf(acc[i][j][r] + bv, 0.f) : 0.f;
        Cp[(size_t)row * 416 + col] = f2bf(v);
      }
    }
  }
}

// ---------------------------------------------------------------------------
// Batched mid GEMM: z=0: out = h1 @ W1t + b1 (raw, bn1 stats);
//                   z=1: si = relu(h1e @ g0t + gb0). BN=64, WM=4, K=416.
__global__ __launch_bounds__(256) void gemm_mid(
    const unsigned short* __restrict__ A0, const unsigned short* __restrict__ W0,
    const float* __restrict__ b0, unsigned short* __restrict__ C0,
    const unsigned short* __restrict__ A1, const unsigned short* __restrict__ W1,
    const float* __restrict__ b1, unsigned short* __restrict__ C1,
    float* __restrict__ sum, float* __restrict__ sumsq)
{
  __shared__ unsigned short As[128 * 32];
  __shared__ unsigned short Bs[64 * 32];
  const bool z1 = blockIdx.z != 0;
  const unsigned short* A = z1 ? A1 : A0;
  const unsigned short* Wt = z1 ? W1 : W0;
  const float* bias = z1 ? b1 : b0;
  unsigned short* C = z1 ? C1 : C0;
  const int row0 = blockIdx.y * 128;
  const int n0 = blockIdx.x * 64;
  const int tid = threadIdx.x;
  const int wid = tid >> 6, lane = tid & 63;
  const int arow = tid >> 2, kcol = (tid & 3) * 8;
  const int lr = lane & 15, lk = (lane >> 4) * 8;
  const int lrow = (lane >> 4) * 4;

  f32x4 acc[2][4] = {};
  for (int k0 = 0; k0 < 416; k0 += 32) {
    gload_lds16(A + (size_t)(row0 + arow) * 416 + k0 + kcol, (char*)As + tid * 16);
    gload_lds16(A + (size_t)(row0 + 64 + arow) * 416 + k0 + kcol, (char*)As + 4096 + tid * 16);
    gload_lds16(Wt + (size_t)(n0 + arow) * 416 + k0 + kcol, (char*)Bs + tid * 16);
    __syncthreads();
    bf16x8 a[2], b[4];
    #pragma unroll
    for (int i = 0; i < 2; ++i)
      a[i] = *reinterpret_cast<const bf16x8*>(&As[(wid * 32 + i * 16 + lr) * 32 + lk]);
    #pragma unroll
    for (int j = 0; j < 4; ++j)
      b[j] = *reinterpret_cast<const bf16x8*>(&Bs[(j * 16 + lr) * 32 + lk]);
    #pragma unroll
    for (int i = 0; i < 2; ++i)
      #pragma unroll
      for (int j = 0; j < 4; ++j)
        acc[i][j] = __builtin_amdgcn_mfma_f32_16x16x32_bf16(a[i], b[j], acc[i][j], 0, 0, 0);
    __syncthreads();
  }
  #pragma unroll
  for (int j = 0; j < 4; ++j) {
    const int col = n0 + j * 16 + lr;
    const float bv = bias[col];
    float s = 0.f, q = 0.f;
    #pragma unroll
    for (int i = 0; i < 2; ++i) {
      #pragma unroll
      for (int r = 0; r < 4; ++r) {
        const int row = row0 + wid * 32 + i * 16 + lrow + r;
        float v = acc[i][j][r] + bv;
        if (z1) v = fmaxf(v, 0.f);
        const unsigned short hv = f2bf(v);
        C[(size_t)row * 256 + col] = hv;
        if (!z1) {
          const float vr = bf2f(hv);
          s += vr;
          q = fmaf(vr, vr, q);
        }
      }
    }
    if (!z1) {
      s += __shfl_xor(s, 16); s += __shfl_xor(s, 32);
      q += __shfl_xor(q, 16); q += __shfl_xor(q, 32);
      if (lane < 16) {
        atomicAdd(&sum[col], s);
        atomicAdd(&sumsq[col], q);
      }
    }
  }
}

// ---------------------------------------------------------------------------
// Generic bf16 MFMA GEMM (used for g1). BM=128, BK=32.
template<int BN, int WM, int WN, int EPI, bool RELU_A>
__global__ __launch_bounds__(256) void gemm_bf16(
    const unsigned short* __restrict__ A, int AS,
    const unsigned short* __restrict__ Wt, const float* __restrict__ bias,
    unsigned short* __restrict__ C, int CS, int Nreal, int NP, int K,
    const unsigned short* __restrict__ emb,
    float* __restrict__ sum, float* __restrict__ sumsq)
{
  constexpr int FRAG_M = 128 / WM / 16;
  constexpr int FRAG_N = BN / WN / 16;
  __shared__ unsigned short As[128 * 32];
  __shared__ unsigned short Bs[BN * 32];
  const int row0 = blockIdx.y * 128;
  const int n0 = blockIdx.x * BN;
  const int tid = threadIdx.x;
  const int wid = tid >> 6, lane = tid & 63;
  const int wr = wid / WN, wc = wid % WN;
  const int arow = tid >> 2;
  const int kcol = (tid & 3) * 8;
  const int lr = lane & 15, lk = (lane >> 4) * 8;
  const int lrow = (lane >> 4) * 4;

  f32x4 acc[FRAG_M][FRAG_N] = {};
  for (int k0 = 0; k0 < K; k0 += 32) {
    gload_lds16(A + (size_t)(row0 + arow) * AS + k0 + kcol, (char*)As + tid * 16);
    gload_lds16(A + (size_t)(row0 + 64 + arow) * AS + k0 + kcol, (char*)As + 4096 + tid * 16);
    gload_lds16(Wt + (size_t)(n0 + arow) * K + k0 + kcol, (char*)Bs + tid * 16);
    if constexpr (BN == 128)
      gload_lds16(Wt + (size_t)(n0 + 64 + arow) * K + k0 + kcol, (char*)Bs + 4096 + tid * 16);
    __syncthreads();
    bf16x8 a[FRAG_M], b[FRAG_N];
    #pragma unroll
    for (int i = 0; i < FRAG_M; ++i) {
      a[i] = *reinterpret_cast<const bf16x8*>(&As[(wr * (128 / WM) + i * 16 + lr) * 32 + lk]);
      if (RELU_A) a[i] = relu_bf8(a[i]);
    }
    #pragma unroll
    for (int j = 0; j < FRAG_N; ++j)
      b[j] = *reinterpret_cast<const bf16x8*>(&Bs[(wc * (BN / WN) + j * 16 + lr) * 32 + lk]);
    #pragma unroll
    for (int i = 0; i < FRAG_M; ++i)
      #pragma unroll
      for (int j = 0; j < FRAG_N; ++j)
        acc[i][j] = __builtin_amdgcn_mfma_f32_16x16x32_bf16(a[i], b[j], acc[i][j], 0, 0, 0);
    __syncthreads();
  }
  #pragma unroll
  for (int j = 0; j < FRAG_N; ++j) {
    const int col = n0 + wc * (BN / WN) + j * 16 + lr;
    if (col >= NP) continue;
    const bool real = col < Nreal;
    const float bv = real ? bias[col] : 0.f;
    float s = 0.f, q = 0.f;
    #pragma unroll
    for (int i = 0; i < FRAG_M; ++i) {
      #pragma unroll
      for (int r = 0; r < 4; ++r) {
        const int row = row0 + wr * (128 / WM) + i * 16 + lrow + r;
        float v = acc[i][j][r] + bv;
        if (EPI == EPI_RELU) v = fmaxf(v, 0.f);
        if (!real) v = 0.f;
        const unsigned short hv = f2bf(v);
        C[(size_t)row * CS + col] = hv;
        if (EPI == EPI_STATS) {
          const float vr = bf2f(hv);
          s += vr;
          q = fmaf(vr, vr, q);
        }
      }
    }
    if (EPI == EPI_STATS) {
      s += __shfl_xor(s, 16); s += __shfl_xor(s, 32);
      q += __shfl_xor(q, 16); q += __shfl_xor(q, 32);
      if (lane < 16) {
        atomicAdd(&sum[col], s);
        atomicAdd(&sumsq[col], q);
      }
    }
  }
}

// ---------------------------------------------------------------------------
// Mod-einsum GEMM (R11-proven form): R5 LDS structure + bijective XCD swizzle.
// 1-D grid of 2048 blocks; swz=(lin&7)*256+lin>>3.
__global__ __launch_bounds__(256) void gemm_mod(
    const unsigned short* __restrict__ A,    // out_bf [16384][256]
    const unsigned short* __restrict__ Wt,   // modWt [2048][256]
    const float* __restrict__ bias, unsigned short* __restrict__ C,
    float* __restrict__ sum, float* __restrict__ sumsq)
{
  __shared__ unsigned short As[128 * 32];
  __shared__ unsigned short Bs[128 * 32];
  const int lin = blockIdx.x;
  const int swz = (lin & 7) * 256 + (lin >> 3);
  const int row0 = (swz >> 4) * 128;
  const int n0 = (swz & 15) * 128;
  const int tid = threadIdx.x;
  const int wid = tid >> 6, lane = tid & 63;
  const int wr = wid >> 1, wc = wid & 1;
  const int arow = tid >> 2;
  const int kcol = (tid & 3) * 8;
  const int lr = lane & 15, lk = (lane >> 4) * 8;
  const int lrow = (lane >> 4) * 4;

  f32x4 acc[4][4] = {};
  for (int k0 = 0; k0 < 256; k0 += 32) {
    gload_lds16(A + (size_t)(row0 + arow) * 256 + k0 + kcol, (char*)As + tid * 16);
    gload_lds16(A + (size_t)(row0 + 64 + arow) * 256 + k0 + kcol, (char*)As + 4096 + tid * 16);
    gload_lds16(Wt + (size_t)(n0 + arow) * 256 + k0 + kcol, (char*)Bs + tid * 16);
    gload_lds16(Wt + (size_t)(n0 + 64 + arow) * 256 + k0 + kcol, (char*)Bs + 4096 + tid * 16);
    __syncthreads();
    bf16x8 a[4], b[4];
    #pragma unroll
    for (int i = 0; i < 4; ++i)
      a[i] = *reinterpret_cast<const bf16x8*>(&As[(wr * 64 + i * 16 + lr) * 32 + lk]);
    #pragma unroll
    for (int j = 0; j < 4; ++j)
      b[j] = *reinterpret_cast<const bf16x8*>(&Bs[(wc * 64 + j * 16 + lr) * 32 + lk]);
    #pragma unroll
    for (int i = 0; i < 4; ++i)
      #pragma unroll
      for (int j = 0; j < 4; ++j)
        acc[i][j] = __builtin_amdgcn_mfma_f32_16x16x32_bf16(a[i], b[j], acc[i][j], 0, 0, 0);
    __syncthreads();
  }
  #pragma unroll
  for (int j = 0; j < 4; ++j) {
    const int col = n0 + wc * 64 + j * 16 + lr;
    const float bv = bias[col];
    float s = 0.f, q = 0.f;
    #pragma unroll
    for (int i = 0; i < 4; ++i) {
      #pragma unroll
      for (int r = 0; r < 4; ++r) {
        const int row = row0 + wr * 64 + i * 16 + lrow + r;
        const unsigned short hv = f2bf(acc[i][j][r] + bv);
        C[(size_t)row * 2048 + col] = hv;
        const float vr = bf2f(hv);
        s += vr;
        q = fmaf(vr, vr, q);
      }
    }
    s += __shfl_xor(s, 16); s += __shfl_xor(s, 32);
    q += __shfl_xor(q, 16); q += __shfl_xor(q, 32);
    if (lane < 16) {
      atomicAdd(&sum[col], s);
      atomicAdd(&sumsq[col], q);
    }
  }
}

// ---------------------------------------------------------------------------
// Fused select iteration (R11-proven).
template<bool RELU_A>
__global__ __launch_bounds__(256) void fused_select(
    const unsigned short* __restrict__ A, const unsigned short* __restrict__ selWt,
    const float* __restrict__ selb, const unsigned short* __restrict__ condWt,
    const float* __restrict__ condb, const unsigned short* __restrict__ emb,
    const float* __restrict__ u, int u_off,
    float* __restrict__ gs, unsigned short* __restrict__ siout)
{
  __shared__ unsigned short As[128 * 32];
  __shared__ unsigned short Bs[64 * 32];
  __shared__ unsigned short Ls[128 * 72];
  const int tid = threadIdx.x;
  const int wid = tid >> 6, lane = tid & 63;
  const int lr = lane & 15, hi = lane >> 4;
  const int lk = hi * 8;
  const int row0 = blockIdx.x * 128;
  const int arow = tid >> 2, kcol = (tid & 3) * 8;

  {
    f32x4 acc[2][4] = {};
    for (int k0 = 0; k0 < 256; k0 += 32) {
      gload_lds16(A + (size_t)(row0 + arow) * 256 + k0 + kcol, (char*)As + tid * 16);
      gload_lds16(A + (size_t)(row0 + 64 + arow) * 256 + k0 + kcol, (char*)As + 4096 + tid * 16);
      gload_lds16(selWt + (size_t)arow * 256 + k0 + kcol, (char*)Bs + tid * 16);
      __syncthreads();
      bf16x8 a[2], b[4];
      #pragma unroll
      for (int i = 0; i < 2; ++i) {
        a[i] = *reinterpret_cast<const bf16x8*>(&As[(wid * 32 + i * 16 + lr) * 32 + lk]);
        if (RELU_A) a[i] = relu_bf8(a[i]);
      }
      #pragma unroll
      for (int j = 0; j < 4; ++j)
        b[j] = *reinterpret_cast<const bf16x8*>(&Bs[(j * 16 + lr) * 32 + lk]);
      #pragma unroll
      for (int i = 0; i < 2; ++i)
        #pragma unroll
        for (int j = 0; j < 4; ++j)
          acc[i][j] = __builtin_amdgcn_mfma_f32_16x16x32_bf16(a[i], b[j], acc[i][j], 0, 0, 0);
      __syncthreads();
    }
    #pragma unroll
    for (int j = 0; j < 4; ++j) {
      const int col = j * 16 + lr;
      const float bv = selb[col];
      #pragma unroll
      for (int i = 0; i < 2; ++i)
        #pragma unroll
        for (int r = 0; r < 4; ++r) {
          const int row = wid * 32 + i * 16 + hi * 4 + r;
          Ls[row * 72 + col] = f2bf(tanhf(acc[i][j][r] + bv));
        }
    }
  }
  __syncthreads();

  #pragma unroll
  for (int p = 0; p < 4; ++p) {
    const int pair = p * 256 + tid;
    const int bl = pair >> 3, mm = pair & 7;
    const int bg = row0 + bl;
    float v[8];
    #pragma unroll
    for (int jj = 0; jj < 8; ++jj) v[jj] = bf2f(Ls[bl * 72 + mm * 8 + jj]);
    const float* up = u + (size_t)bg * 192 + u_off + mm * 8;
    #pragma unroll
    for (int jj = 0; jj < 8; ++jj) {
      const float uu = fminf(fmaxf(up[jj], 1e-10f), 0.9999999f);
      v[jj] -= logf(-logf(uu));
    }
    float mx = v[0];
    #pragma unroll
    for (int jj = 1; jj < 8; ++jj) mx = fmaxf(mx, v[jj]);
    float s = 0.f;
    #pragma unroll
    for (int jj = 0; jj < 8; ++jj) { v[jj] = expf(v[jj] - mx); s += v[jj]; }
    const float inv = 1.f / s;
    float* op = gs + (size_t)bg * 64 + mm * 8;
    #pragma unroll
    for (int jj = 0; jj < 8; ++jj) op[jj] = v[jj] * inv;
  }

  {
    const int wr2 = wid >> 1, wc2 = wid & 1;
    f32x4 acc2[4][8] = {};
    #pragma unroll
    for (int kq = 0; kq < 2; ++kq) {
      const int k0 = kq * 32;
      bf16x8 a2[4];
      #pragma unroll
      for (int i = 0; i < 4; ++i)
        a2[i] = *reinterpret_cast<const bf16x8*>(
            &Ls[(wr2 * 64 + i * 16 + lr) * 72 + k0 + hi * 8]);
      #pragma unroll
      for (int j = 0; j < 8; ++j) {
        const bf16x8 b2 = *reinterpret_cast<const bf16x8*>(
            condWt + (size_t)(wc2 * 128 + j * 16 + lr) * 64 + k0 + hi * 8);
        #pragma unroll
        for (int i = 0; i < 4; ++i)
          acc2[i][j] = __builtin_amdgcn_mfma_f32_16x16x32_bf16(a2[i], b2, acc2[i][j], 0, 0, 0);
      }
    }
    #pragma unroll
    for (int j = 0; j < 8; ++j) {
      const int col = wc2 * 128 + j * 16 + lr;
      const float bv = condb[col];
      #pragma unroll
      for (int i = 0; i < 4; ++i)
        #pragma unroll
        for (int r = 0; r < 4; ++r) {
          const int row = row0 + wr2 * 64 + i * 16 + hi * 4 + r;
          float vv = (acc2[i][j][r] + bv) * bf2f(emb[(size_t)row * 256 + col]);
          siout[(size_t)row * 256 + col] = f2bf(fmaxf(vv, 0.f));
        }
    }
  }
}

// ---------------------------------------------------------------------------
// Final select: MFMA GEMM (K=256, N=16 pad, 8 real) + gumbel epilogue.
__global__ __launch_bounds__(256) void gemm_fsel(
    const unsigned short* __restrict__ A, const unsigned short* __restrict__ Wt,
    const float* __restrict__ bias, const float* __restrict__ u,
    float* __restrict__ fs)
{
  __shared__ unsigned short As[128 * 32];
  __shared__ unsigned short Bs[16 * 32];
  const int row0 = blockIdx.y * 128;
  const int tid = threadIdx.x;
  const int wid = tid >> 6, lane = tid & 63;
  const int arow = tid >> 2, kcol = (tid & 3) * 8;
  const int lr = lane & 15, hi = lane >> 4;
  const int lk = hi * 8;

  f32x4 acc[2] = {};
  for (int k0 = 0; k0 < 256; k0 += 32) {
    gload_lds16(A + (size_t)(row0 + arow) * 256 + k0 + kcol, (char*)As + tid * 16);
    gload_lds16(A + (size_t)(row0 + 64 + arow) * 256 + k0 + kcol, (char*)As + 4096 + tid * 16);
    if (wid == 0)
      gload_lds16(Wt + (size_t)(lane >> 2) * 256 + k0 + (lane & 3) * 8, (char*)Bs + lane * 16);
    __syncthreads();
    bf16x8 a[2];
    #pragma unroll
    for (int i = 0; i < 2; ++i)
      a[i] = *reinterpret_cast<const bf16x8*>(&As[(wid * 32 + i * 16 + lr) * 32 + lk]);
    const bf16x8 b = *reinterpret_cast<const bf16x8*>(&Bs[lr * 32 + lk]);
    #pragma unroll
    for (int i = 0; i < 2; ++i)
      acc[i] = __builtin_amdgcn_mfma_f32_16x16x32_bf16(a[i], b, acc[i], 0, 0, 0);
    __syncthreads();
  }
  const float bv = (lr < 8) ? bias[lr] : 0.f;
  #pragma unroll
  for (int i = 0; i < 2; ++i) {
    #pragma unroll
    for (int r = 0; r < 4; ++r) {
      const int row = row0 + wid * 32 + i * 16 + hi * 4 + r;
      float v = acc[i][r] + bv;
      if (lr < 8) {
        const float uu = fminf(fmaxf(u[(size_t)row * 8 + lr], 1e-10f), 0.9999999f);
        v -= logf(-logf(uu));
      }
      float mx = v;
      mx = fmaxf(mx, __shfl_xor(mx, 1));
      mx = fmaxf(mx, __shfl_xor(mx, 2));
      mx = fmaxf(mx, __shfl_xor(mx, 4));
      const float e = expf(v - mx);
      float ssum = e;
      ssum += __shfl_xor(ssum, 1);
      ssum += __shfl_xor(ssum, 2);
      ssum += __shfl_xor(ssum, 4);
      if (lr < 8) fs[(size_t)row * 8 + lr] = e / ssum;
    }
  }
}

// ---------------------------------------------------------------------------
// Fold mod weights with inline bn1 finalize. grid (8, 8, 9).
__global__ __launch_bounds__(256) void fold_modw_all(
    const float* __restrict__ W, const float* __restrict__ g1,
    const float* __restrict__ b1, const float* __restrict__ modb,
    const float* __restrict__ sum1, const float* __restrict__ sumsq1,
    unsigned short* __restrict__ Wt, float* __restrict__ bias2)
{
  const float invB = 1.f / 16384.f;
  if (blockIdx.z == 8) {
    if (blockIdx.y != 0) return;
    const int m = blockIdx.x, h = threadIdx.x;
    float acc = modb[m * 256 + h];
    for (int d = 0; d < 256; ++d) {
      const float mean = sum1[d] * invB;
      const float var = sumsq1[d] * invB - mean * mean;
      const float r = rsqrtf(var + 1e-5f);
      const float c = b1[m * 256 + d] - mean * r * g1[m * 256 + d];
      acc = fmaf(c, W[((size_t)m * 256 + d) * 256 + h], acc);
    }
    bias2[m * 256 + h] = acc;
    return;
  }
  __shared__ float t[32][33];
  const int m = blockIdx.z, d0 = blockIdx.y * 32, h0 = blockIdx.x * 32;
  const int tx = threadIdx.x & 31, ty = threadIdx.x >> 5;
  #pragma unroll
  for (int p = 0; p < 4; ++p) {
    const int d = d0 + ty + p * 8;
    const float mean = sum1[d] * invB;
    const float var = sumsq1[d] * invB - mean * mean;
    const float r = rsqrtf(var + 1e-5f);
    t[ty + p * 8][tx] = W[((size_t)m * 256 + d) * 256 + h0 + tx] * r * g1[m * 256 + d];
  }
  __syncthreads();
  #pragma unroll
  for (int p = 0; p < 4; ++p) {
    const int h = h0 + ty + p * 8;
    Wt[((size_t)m * 256 + h) * 256 + d0 + tx] = f2bf(t[tx][ty + p * 8]);
  }
}

// bn2 finalize.
__global__ void finalize_bn2(const float* __restrict__ sum, const float* __restrict__ sumsq,
                             const float* __restrict__ g, const float* __restrict__ b,
                             float* __restrict__ scale, float* __restrict__ shift)
{
  const int i = blockIdx.x * 256 + threadIdx.x;
  const float invB = 1.f / 16384.f;
  const float m = sum[i] * invB;
  const float v = sumsq[i] * invB - m * m;
  const float r = rsqrtf(v + 1e-5f);
  const float sc = r * g[i];
  scale[i] = sc;
  shift[i] = b[i] - m * sc;
}

// ---------------------------------------------------------------------------
// Cascade (R5-proven).
__global__ __launch_bounds__(256) void final_cascade(
    const unsigned short* __restrict__ H, const float* __restrict__ scale2,
    const float* __restrict__ shift2, const float* __restrict__ gs0,
    const float* __restrict__ gs1, const float* __restrict__ gs2,
    const float* __restrict__ fs, unsigned short* __restrict__ ovec)
{
  const int wave = threadIdx.x >> 6, lane = threadIdx.x & 63;
  const int b = __builtin_amdgcn_readfirstlane(blockIdx.x * 4 + wave);
  const int c0 = lane << 2;

  float prev[8][4];
  #pragma unroll
  for (int m = 0; m < 8; ++m) {
    const int gc = m * 256 + c0;
    const ushort4 h = *reinterpret_cast<const ushort4*>(&H[(size_t)b * 2048 + gc]);
    const float4 sc = *reinterpret_cast<const float4*>(&scale2[gc]);
    const float4 sh = *reinterpret_cast<const float4*>(&shift2[gc]);
    prev[m][0] = bf2f(h.x) * sc.x + sh.x;
    prev[m][1] = bf2f(h.y) * sc.y + sh.y;
    prev[m][2] = bf2f(h.z) * sc.z + sh.z;
    prev[m][3] = bf2f(h.w) * sc.w + sh.w;
  }

  const float* sel0 = gs2 + (size_t)b * 64;
  const float* sel1 = gs1 + (size_t)b * 64;
  const float* sel2 = gs0 + (size_t)b * 64;
  #pragma unroll
  for (int l = 0; l < 3; ++l) {
    const float* sp = (l == 0) ? sel0 : (l == 1) ? sel1 : sel2;
    float nw[8][4];
    #pragma unroll
    for (int m = 0; m < 8; ++m) {
      float a0 = 0.f, a1 = 0.f, a2 = 0.f, a3 = 0.f;
      #pragma unroll
      for (int k = 0; k < 8; ++k) {
        const float s = sp[m * 8 + k];
        a0 = fmaf(s, prev[k][0], a0);
        a1 = fmaf(s, prev[k][1], a1);
        a2 = fmaf(s, prev[k][2], a2);
        a3 = fmaf(s, prev[k][3], a3);
      }
      nw[m][0] = fmaxf(a0, 0.f); nw[m][1] = fmaxf(a1, 0.f);
      nw[m][2] = fmaxf(a2, 0.f); nw[m][3] = fmaxf(a3, 0.f);
    }
    #pragma unroll
    for (int m = 0; m < 8; ++m)
      #pragma unroll
      for (int c = 0; c < 4; ++c)
        prev[m][c] = nw[m][c];
  }

  const float* fp = fs + (size_t)b * 8;
  float ov[4] = {0.f, 0.f, 0.f, 0.f};
  #pragma unroll
  for (int m = 0; m < 8; ++m) {
    const float s = fp[m];
    ov[0] = fmaf(s, prev[m][0], ov[0]);
    ov[1] = fmaf(s, prev[m][1], ov[1]);
    ov[2] = fmaf(s, prev[m][2], ov[2]);
    ov[3] = fmaf(s, prev[m][3], ov[3]);
  }
  ushort4 o;
  o.x = f2bf(ov[0]); o.y = f2bf(ov[1]); o.z = f2bf(ov[2]); o.w = f2bf(ov[3]);
  *reinterpret_cast<ushort4*>(&ovec[(size_t)b * 256 + c0]) = o;
}

// ---------------------------------------------------------------------------
// Last GEMM (R5-proven).
__global__ __launch_bounds__(256) void gemm_last(
    const unsigned short* __restrict__ A, const unsigned short* __restrict__ Wt,
    const float* __restrict__ bias, float* __restrict__ out)
{
  __shared__ unsigned short As[128 * 32];
  __shared__ unsigned short Bs[64 * 32];
  const int row0 = blockIdx.y * 128;
  const int tid = threadIdx.x;
  const int wid = tid >> 6, lane = tid & 63;
  const int arow = tid >> 2;
  const int kcol = (tid & 3) * 8;
  const int lr = lane & 15, lk = (lane >> 4) * 8;
  const int lrow = (lane >> 4) * 4;

  f32x4 acc[2][4] = {};
  for (int k0 = 0; k0 < 256; k0 += 32) {
    gload_lds16(A + (size_t)(row0 + arow) * 256 + k0 + kcol, (char*)As + tid * 16);
    gload_lds16(A + (size_t)(row0 + 64 + arow) * 256 + k0 + kcol, (char*)As + 4096 + tid * 16);
    gload_lds16(Wt + (size_t)arow * 256 + k0 + kcol, (char*)Bs + tid * 16);
    __syncthreads();
    bf16x8 a[2], b[4];
    #pragma unroll
    for (int i = 0; i < 2; ++i)
      a[i] = *reinterpret_cast<const bf16x8*>(&As[(wid * 32 + i * 16 + lr) * 32 + lk]);
    #pragma unroll
    for (int j = 0; j < 4; ++j)
      b[j] = *reinterpret_cast<const bf16x8*>(&Bs[(j * 16 + lr) * 32 + lk]);
    #pragma unroll
    for (int i = 0; i < 2; ++i)
      #pragma unroll
      for (int j = 0; j < 4; ++j)
        acc[i][j] = __builtin_amdgcn_mfma_f32_16x16x32_bf16(a[i], b[j], acc[i][j], 0, 0, 0);
    __syncthreads();
  }
  #pragma unroll
  for (int j = 0; j < 2; ++j) {
    const int col = j * 16 + lr;
    if (col >= 18) continue;
    const float bv = bias[col];
    #pragma unroll
    for (int i = 0; i < 2; ++i) {
      #pragma unroll
      for (int r = 0; r < 4; ++r) {
        const int row = row0 + wid * 32 + i * 16 + lrow + r;
        out[(size_t)row * 18 + col] = acc[i][j][r] + bv;
      }
    }
  }
}

extern "C" void kernel_launch(void* const* d_in, const int* in_sizes, int n_in,
                              void* d_out, int out_size, void* d_ws, size_t ws_size,
                              hipStream_t stream)
{
  (void)in_sizes; (void)n_in; (void)out_size; (void)ws_size;
  const float* x       = (const float*)d_in[0];
  const float* embi    = (const float*)d_in[1];
  const float* u_sel   = (const float*)d_in[2];
  const float* u_fin   = (const float*)d_in[3];
  const float* base_W0 = (const float*)d_in[4];
  const float* base_b0 = (const float*)d_in[5];
  const float* base_W1 = (const float*)d_in[6];
  const float* base_b1 = (const float*)d_in[7];
  const float* em_W0   = (const float*)d_in[8];
  const float* em_b0   = (const float*)d_in[9];
  const float* gat_W0  = (const float*)d_in[10];
  const float* gat_b0  = (const float*)d_in[11];
  const float* gat_W1  = (const float*)d_in[12];
  const float* gat_b1  = (const float*)d_in[13];
  const float* sel_W   = (const float*)d_in[14];
  const float* sel_b   = (const float*)d_in[15];
  const float* selF_W  = (const float*)d_in[16];
  const float* selF_b  = (const float*)d_in[17];
  const float* cond_W  = (const float*)d_in[18];
  const float* cond_b  = (const float*)d_in[19];
  const float* mod_W   = (const float*)d_in[20];
  const float* mod_b   = (const float*)d_in[21];
  const float* last_W  = (const float*)d_in[22];
  const float* last_b  = (const float*)d_in[23];
  const float* bn1_g   = (const float*)d_in[24];
  const float* bn1_b   = (const float*)d_in[25];
  const float* bn2_g   = (const float*)d_in[26];
  const float* bn2_b   = (const float*)d_in[27];

  // --- workspace layout (byte offsets) ---
  char* WSB = (char*)d_ws;
  unsigned short* h_big    = (unsigned short*)(WSB + 0);          // 16384x2048 bf16
  unsigned short* h1e      = (unsigned short*)(WSB + 67108864);   // 16384x416 (em)
  unsigned short* ovec_bf  = (unsigned short*)(WSB + 67108864);   // overlaps dead h1e
  unsigned short* h1       = (unsigned short*)(WSB + 81000448);   // 16384x416 (base)
  unsigned short* emb_bf   = (unsigned short*)(WSB + 103020544);  // 16384x256
  unsigned short* si_bf    = (unsigned short*)(WSB + 111409152);  // 16384x256
  unsigned short* out_bf   = (unsigned short*)(WSB + 119797760);  // 16384x256
  float* gs0   = (float*)(WSB + 130283520);  // 16384x64
  float* gs1   = (float*)(WSB + 134477824);
  float* gs2   = (float*)(WSB + 138672128);
  float* bufFs = (float*)(WSB + 142866432);  // 16384x8
  unsigned short* W0t   = (unsigned short*)(WSB + 143390720);  // 512x128
  unsigned short* emW0t = (unsigned short*)(WSB + 143521792);  // 512x128
  unsigned short* W1t   = (unsigned short*)(WSB + 143652864);  // 256x416
  unsigned short* g0t   = (unsigned short*)(WSB + 143865856);  // 256x416
  unsigned short* g1t   = (unsigned short*)(WSB + 144078848);  // 256x256
  unsigned short* selWt = (unsigned short*)(WSB + 144209920);  // 3x64x256
  unsigned short* condWt= (unsigned short*)(WSB + 144308224);  // 3x256x64
  unsigned short* modWt = (unsigned short*)(WSB + 144406528);  // 8x256x256
  float* bias2  = (float*)(WSB + 146503680);  // 2048
  float* stats  = (float*)(WSB + 146511872);  // 4608 floats
  unsigned short* lastWt = (unsigned short*)(WSB + 146530304); // 64x256 bf16
  float* scale2 = (float*)(WSB + 146563072);  // 2048
  float* shift2 = (float*)(WSB + 146571264);  // 2048
  unsigned short* selFt = (unsigned short*)(WSB + 146579456);  // 16x256 bf16
  float* sum1   = stats;        float* sumsq1 = stats + 256;
  float* sum2   = stats + 512;  float* sumsq2 = stats + 2560;

  const dim3 blk(256);
  // prep (weight transposes + selFt + stats zero)
  prep_all<<<dim3(506), blk, 0, stream>>>(
      base_W0, em_W0, base_W1, gat_W0, gat_W1, sel_W, cond_W, last_W, selF_W,
      W0t, emW0t, W1t, g0t, g1t, selWt, condWt, lastWt, selFt, stats);

  // batched W0 GEMMs from fp32 inputs
  gemm_w0<<<dim3(4, 128, 2), blk, 0, stream>>>(
      x, embi, W0t, emW0t, base_b0, em_b0, h1, h1e);
  // batched mid GEMMs: z=0 W1->out (bn1 stats), z=1 g0->si (relu)
  gemm_mid<<<dim3(4, 128, 2), blk, 0, stream>>>(
      h1, W1t, base_b1, out_bf, h1e, g0t, gat_b0, si_bf, sum1, sumsq1);
  // g1 -> emb
  gemm_bf16<64, 4, 1, EPI_NONE, false><<<dim3(4, 128), blk, 0, stream>>>(
      si_bf, 256, g1t, gat_b1, emb_bf, 256, 256, 256, 256, nullptr, nullptr, nullptr);
  // fused select loop
  fused_select<true><<<dim3(128), blk, 0, stream>>>(
      emb_bf, selWt, sel_b, condWt, cond_b, emb_bf, u_sel, 0, gs0, si_bf);
  fused_select<false><<<dim3(128), blk, 0, stream>>>(
      si_bf, selWt + 16384, sel_b + 64, condWt + 16384, cond_b + 256, emb_bf,
      u_sel, 64, gs1, si_bf);
  fused_select<false><<<dim3(128), blk, 0, stream>>>(
      si_bf, selWt + 32768, sel_b + 128, condWt + 32768, cond_b + 512, emb_bf,
      u_sel, 128, gs2, si_bf);
  // final select (MFMA)
  gemm_fsel<<<dim3(1, 128), blk, 0, stream>>>(si_bf, selFt, selF_b, u_fin, bufFs);
  // bn1 finalize + mod weight fold + bias2
  fold_modw_all<<<dim3(8, 8, 9), blk, 0, stream>>>(
      mod_W, bn1_g, bn1_b, mod_b, sum1, sumsq1, modWt, bias2);
  // mod einsum -> h_big (fused bn2 stats)
  gemm_mod<<<dim3(2048), blk, 0, stream>>>(out_bf, modWt, bias2, h_big, sum2, sumsq2);
  finalize_bn2<<<dim3(8), blk, 0, stream>>>(sum2, sumsq2, bn2_g, bn2_b, scale2, shift2);
  // cascade -> ovec, then last GEMM -> d_out
  final_cascade<<<dim3(4096), blk, 0, stream>>>(
      h_big, scale2, shift2, gs0, gs1, gs2, bufFs, ovec_bf);
  gemm_last<<<dim3(1, 128), blk, 0, stream>>>(ovec_bf, lastWt, last_b, (float*)d_out);
}

// Round 16
// 244.724 us; speedup vs baseline: 1.0469x; 1.0120x over previous
//
#include <hip/hip_runtime.h>
#include <math.h>

// ---------------------------------------------------------------------------
// ModularSelectCascadeNet forward. B=16384, M=8, NUM_LAYERS=4.
// R16 = R15 + {final_cascade, gemm_last} fused into cascade_last (ovec lives
//       in LDS; wave 0 runs the 16x18 last GEMM). 13 dispatches.
// ---------------------------------------------------------------------------

typedef short bf16x8 __attribute__((ext_vector_type(8)));
typedef float f32x4 __attribute__((ext_vector_type(4)));

__device__ __forceinline__ unsigned short f2bf(float f) {
  unsigned u = __float_as_uint(f);
  u += 0x7fffu + ((u >> 16) & 1u);
  return (unsigned short)(u >> 16);
}
__device__ __forceinline__ float bf2f(unsigned short h) {
  return __uint_as_float(((unsigned)h) << 16);
}
__device__ __forceinline__ unsigned pack2(float a, float b) {
  return ((unsigned)f2bf(b) << 16) | f2bf(a);
}
__device__ __forceinline__ void gload_lds16(const void* g, void* l) {
  __builtin_amdgcn_global_load_lds(
      (const __attribute__((address_space(1))) unsigned int*)g,
      (__attribute__((address_space(3))) unsigned int*)l, 16, 0, 0);
}
__device__ __forceinline__ bf16x8 relu_bf8(bf16x8 v) {
  bf16x8 r;
  #pragma unroll
  for (int j = 0; j < 8; ++j) r[j] = v[j] > 0 ? v[j] : (short)0;
  return r;
}

#define EPI_NONE  0
#define EPI_RELU  1
#define EPI_STATS 4

// ---------------------------------------------------------------------------
// Prep: weight transposes + lastW + selFt + stats zero. 506 blocks.
__global__ __launch_bounds__(256) void prep_all(
    const float* __restrict__ base_W0, const float* __restrict__ em_W0,
    const float* __restrict__ base_W1, const float* __restrict__ gat_W0,
    const float* __restrict__ gat_W1, const float* __restrict__ sel_W,
    const float* __restrict__ cond_W, const float* __restrict__ last_W,
    const float* __restrict__ selF_W,
    unsigned short* __restrict__ W0t, unsigned short* __restrict__ emW0t,
    unsigned short* __restrict__ W1t, unsigned short* __restrict__ g0t,
    unsigned short* __restrict__ g1t, unsigned short* __restrict__ selWt,
    unsigned short* __restrict__ condWt, unsigned short* __restrict__ lastWt,
    unsigned short* __restrict__ selFt, float* __restrict__ stats)
{
  __shared__ float t[32][33];
  int bid = blockIdx.x;
  const int tid = threadIdx.x;
  const int tx = tid & 31, ty = tid >> 5;

  if (bid < 496) {
    const float* src; unsigned short* dst; int K, N, KP, gx, local;
    if (bid < 64)       { src = base_W0; dst = W0t;   K = 128; N = 400; KP = 128; gx = 4;  local = bid; }
    else if (bid < 128) { src = em_W0;   dst = emW0t; K = 128; N = 400; KP = 128; gx = 4;  local = bid - 64; }
    else if (bid < 232) { src = base_W1; dst = W1t;   K = 400; N = 256; KP = 416; gx = 13; local = bid - 128; }
    else if (bid < 336) { src = gat_W0;  dst = g0t;   K = 400; N = 256; KP = 416; gx = 13; local = bid - 232; }
    else if (bid < 400) { src = gat_W1;  dst = g1t;   K = 256; N = 256; KP = 256; gx = 8;  local = bid - 336; }
    else if (bid < 448) {
      const int i = (bid - 400) / 16;
      src = sel_W + i * 16384; dst = selWt + i * 16384;
      K = 256; N = 64; KP = 256; gx = 8; local = (bid - 400) % 16;
    } else {
      const int i = (bid - 448) / 16;
      src = cond_W + i * 16384; dst = condWt + i * 16384;
      K = 64; N = 256; KP = 64; gx = 2; local = (bid - 448) % 16;
    }
    const int k0 = (local % gx) * 32, n0 = (local / gx) * 32;
    #pragma unroll
    for (int p = 0; p < 4; ++p) {
      const int k = k0 + ty + p * 8;
      t[ty + p * 8][tx] = (k < K && n0 + tx < N) ? src[(size_t)k * N + n0 + tx] : 0.f;
    }
    __syncthreads();
    #pragma unroll
    for (int p = 0; p < 4; ++p) {
      const int n = n0 + ty + p * 8;
      dst[(size_t)n * KP + k0 + tx] = f2bf(t[tx][ty + p * 8]);
    }
    return;
  }
  bid -= 496;

  if (bid < 8) {
    const int k0 = bid * 32;
    #pragma unroll
    for (int p = 0; p < 4; ++p)
      t[ty + p * 8][tx] = (tx < 18) ? last_W[(size_t)(k0 + ty + p * 8) * 18 + tx] : 0.f;
    __syncthreads();
    #pragma unroll
    for (int p = 0; p < 4; ++p) {
      const int n = ty + p * 8;
      lastWt[(size_t)n * 256 + k0 + tx] = f2bf(t[tx][n]);
      lastWt[(size_t)(n + 32) * 256 + k0 + tx] = 0;
    }
    return;
  }
  bid -= 8;

  if (bid == 0) {  // selFt: [256][8] f32 -> bf16 [16][256] (rows 8..15 zero)
    const int k = tid;
    #pragma unroll
    for (int j = 0; j < 8; ++j) selFt[j * 256 + k] = f2bf(selF_W[k * 8 + j]);
    #pragma unroll
    for (int j = 8; j < 16; ++j) selFt[j * 256 + k] = 0;
    return;
  }

  for (int i = tid; i < 4608; i += 256) stats[i] = 0.f;
}

// ---------------------------------------------------------------------------
// W0 GEMM (fp32 A, converted during reg->LDS staging). grid (4, 128, 2).
__global__ __launch_bounds__(256) void gemm_w0(
    const float* __restrict__ Ax, const float* __restrict__ Ae,
    const unsigned short* __restrict__ Wx, const unsigned short* __restrict__ We,
    const float* __restrict__ bx, const float* __restrict__ be,
    unsigned short* __restrict__ Cx, unsigned short* __restrict__ Ce)
{
  __shared__ unsigned short As[128 * 32];
  __shared__ unsigned short Bs[128 * 32];
  const float* Ap = blockIdx.z ? Ae : Ax;
  const unsigned short* Wp = blockIdx.z ? We : Wx;
  const float* bp = blockIdx.z ? be : bx;
  unsigned short* Cp = blockIdx.z ? Ce : Cx;
  const int row0 = blockIdx.y * 128;
  const int n0 = blockIdx.x * 128;
  const int tid = threadIdx.x;
  const int wid = tid >> 6, lane = tid & 63;
  const int wr = wid >> 1, wc = wid & 1;
  const int arow = tid >> 2, kcol = (tid & 3) * 8;
  const int lr = lane & 15, lk = (lane >> 4) * 8;
  const int lrow = (lane >> 4) * 4;

  f32x4 acc[4][4] = {};
  for (int k0 = 0; k0 < 128; k0 += 32) {
    {
      const float4* s1 = reinterpret_cast<const float4*>(
          Ap + (size_t)(row0 + arow) * 128 + k0 + kcol);
      uint4 w1 = {pack2(s1[0].x, s1[0].y), pack2(s1[0].z, s1[0].w),
                  pack2(s1[1].x, s1[1].y), pack2(s1[1].z, s1[1].w)};
      *reinterpret_cast<uint4*>(&As[arow * 32 + kcol]) = w1;
      const float4* s2 = reinterpret_cast<const float4*>(
          Ap + (size_t)(row0 + 64 + arow) * 128 + k0 + kcol);
      uint4 w2 = {pack2(s2[0].x, s2[0].y), pack2(s2[0].z, s2[0].w),
                  pack2(s2[1].x, s2[1].y), pack2(s2[1].z, s2[1].w)};
      *reinterpret_cast<uint4*>(&As[(64 + arow) * 32 + kcol]) = w2;
    }
    gload_lds16(Wp + (size_t)(n0 + arow) * 128 + k0 + kcol, (char*)Bs + tid * 16);
    gload_lds16(Wp + (size_t)(n0 + 64 + arow) * 128 + k0 + kcol,
                (char*)Bs + 4096 + tid * 16);
    __syncthreads();
    bf16x8 a[4], b[4];
    #pragma unroll
    for (int i = 0; i < 4; ++i)
      a[i] = *reinterpret_cast<const bf16x8*>(&As[(wr * 64 + i * 16 + lr) * 32 + lk]);
    #pragma unroll
    for (int j = 0; j < 4; ++j)
      b[j] = *reinterpret_cast<const bf16x8*>(&Bs[(wc * 64 + j * 16 + lr) * 32 + lk]);
    #pragma unroll
    for (int i = 0; i < 4; ++i)
      #pragma unroll
      for (int j = 0; j < 4; ++j)
        acc[i][j] = __builtin_amdgcn_mfma_f32_16x16x32_bf16(a[i], b[j], acc[i][j], 0, 0, 0);
    __syncthreads();
  }
  #pragma unroll
  for (int j = 0; j < 4; ++j) {
    const int col = n0 + wc * 64 + j * 16 + lr;
    if (col >= 416) continue;
    const bool real = col < 400;
    const float bv = real ? bp[col] : 0.f;
    #pragma unroll
    for (int i = 0; i < 4; ++i) {
      #pragma unroll
      for (int r = 0; r < 4; ++r) {
        const int row = row0 + wr * 64 + i * 16 + lrow + r;
        float v = real ? fmaxf(acc[i][j][r] + bv, 0.f) : 0.f;
        Cp[(size_t)row * 416 + col] = f2bf(v);
      }
    }
  }
}

// ---------------------------------------------------------------------------
// Batched mid GEMM: z=0: out = h1 @ W1t + b1 (raw, bn1 stats);
//                   z=1: si = relu(h1e @ g0t + gb0). BN=64, WM=4, K=416.
__global__ __launch_bounds__(256) void gemm_mid(
    const unsigned short* __restrict__ A0, const unsigned short* __restrict__ W0,
    const float* __restrict__ b0, unsigned short* __restrict__ C0,
    const unsigned short* __restrict__ A1, const unsigned short* __restrict__ W1,
    const float* __restrict__ b1, unsigned short* __restrict__ C1,
    float* __restrict__ sum, float* __restrict__ sumsq)
{
  __shared__ unsigned short As[128 * 32];
  __shared__ unsigned short Bs[64 * 32];
  const bool z1 = blockIdx.z != 0;
  const unsigned short* A = z1 ? A1 : A0;
  const unsigned short* Wt = z1 ? W1 : W0;
  const float* bias = z1 ? b1 : b0;
  unsigned short* C = z1 ? C1 : C0;
  const int row0 = blockIdx.y * 128;
  const int n0 = blockIdx.x * 64;
  const int tid = threadIdx.x;
  const int wid = tid >> 6, lane = tid & 63;
  const int arow = tid >> 2, kcol = (tid & 3) * 8;
  const int lr = lane & 15, lk = (lane >> 4) * 8;
  const int lrow = (lane >> 4) * 4;

  f32x4 acc[2][4] = {};
  for (int k0 = 0; k0 < 416; k0 += 32) {
    gload_lds16(A + (size_t)(row0 + arow) * 416 + k0 + kcol, (char*)As + tid * 16);
    gload_lds16(A + (size_t)(row0 + 64 + arow) * 416 + k0 + kcol, (char*)As + 4096 + tid * 16);
    gload_lds16(Wt + (size_t)(n0 + arow) * 416 + k0 + kcol, (char*)Bs + tid * 16);
    __syncthreads();
    bf16x8 a[2], b[4];
    #pragma unroll
    for (int i = 0; i < 2; ++i)
      a[i] = *reinterpret_cast<const bf16x8*>(&As[(wid * 32 + i * 16 + lr) * 32 + lk]);
    #pragma unroll
    for (int j = 0; j < 4; ++j)
      b[j] = *reinterpret_cast<const bf16x8*>(&Bs[(j * 16 + lr) * 32 + lk]);
    #pragma unroll
    for (int i = 0; i < 2; ++i)
      #pragma unroll
      for (int j = 0; j < 4; ++j)
        acc[i][j] = __builtin_amdgcn_mfma_f32_16x16x32_bf16(a[i], b[j], acc[i][j], 0, 0, 0);
    __syncthreads();
  }
  #pragma unroll
  for (int j = 0; j < 4; ++j) {
    const int col = n0 + j * 16 + lr;
    const float bv = bias[col];
    float s = 0.f, q = 0.f;
    #pragma unroll
    for (int i = 0; i < 2; ++i) {
      #pragma unroll
      for (int r = 0; r < 4; ++r) {
        const int row = row0 + wid * 32 + i * 16 + lrow + r;
        float v = acc[i][j][r] + bv;
        if (z1) v = fmaxf(v, 0.f);
        const unsigned short hv = f2bf(v);
        C[(size_t)row * 256 + col] = hv;
        if (!z1) {
          const float vr = bf2f(hv);
          s += vr;
          q = fmaf(vr, vr, q);
        }
      }
    }
    if (!z1) {
      s += __shfl_xor(s, 16); s += __shfl_xor(s, 32);
      q += __shfl_xor(q, 16); q += __shfl_xor(q, 32);
      if (lane < 16) {
        atomicAdd(&sum[col], s);
        atomicAdd(&sumsq[col], q);
      }
    }
  }
}

// ---------------------------------------------------------------------------
// Generic bf16 MFMA GEMM (used for g1). BM=128, BK=32.
template<int BN, int WM, int WN, int EPI, bool RELU_A>
__global__ __launch_bounds__(256) void gemm_bf16(
    const unsigned short* __restrict__ A, int AS,
    const unsigned short* __restrict__ Wt, const float* __restrict__ bias,
    unsigned short* __restrict__ C, int CS, int Nreal, int NP, int K,
    const unsigned short* __restrict__ emb,
    float* __restrict__ sum, float* __restrict__ sumsq)
{
  constexpr int FRAG_M = 128 / WM / 16;
  constexpr int FRAG_N = BN / WN / 16;
  __shared__ unsigned short As[128 * 32];
  __shared__ unsigned short Bs[BN * 32];
  const int row0 = blockIdx.y * 128;
  const int n0 = blockIdx.x * BN;
  const int tid = threadIdx.x;
  const int wid = tid >> 6, lane = tid & 63;
  const int wr = wid / WN, wc = wid % WN;
  const int arow = tid >> 2;
  const int kcol = (tid & 3) * 8;
  const int lr = lane & 15, lk = (lane >> 4) * 8;
  const int lrow = (lane >> 4) * 4;

  f32x4 acc[FRAG_M][FRAG_N] = {};
  for (int k0 = 0; k0 < K; k0 += 32) {
    gload_lds16(A + (size_t)(row0 + arow) * AS + k0 + kcol, (char*)As + tid * 16);
    gload_lds16(A + (size_t)(row0 + 64 + arow) * AS + k0 + kcol, (char*)As + 4096 + tid * 16);
    gload_lds16(Wt + (size_t)(n0 + arow) * K + k0 + kcol, (char*)Bs + tid * 16);
    if constexpr (BN == 128)
      gload_lds16(Wt + (size_t)(n0 + 64 + arow) * K + k0 + kcol, (char*)Bs + 4096 + tid * 16);
    __syncthreads();
    bf16x8 a[FRAG_M], b[FRAG_N];
    #pragma unroll
    for (int i = 0; i < FRAG_M; ++i) {
      a[i] = *reinterpret_cast<const bf16x8*>(&As[(wr * (128 / WM) + i * 16 + lr) * 32 + lk]);
      if (RELU_A) a[i] = relu_bf8(a[i]);
    }
    #pragma unroll
    for (int j = 0; j < FRAG_N; ++j)
      b[j] = *reinterpret_cast<const bf16x8*>(&Bs[(wc * (BN / WN) + j * 16 + lr) * 32 + lk]);
    #pragma unroll
    for (int i = 0; i < FRAG_M; ++i)
      #pragma unroll
      for (int j = 0; j < FRAG_N; ++j)
        acc[i][j] = __builtin_amdgcn_mfma_f32_16x16x32_bf16(a[i], b[j], acc[i][j], 0, 0, 0);
    __syncthreads();
  }
  #pragma unroll
  for (int j = 0; j < FRAG_N; ++j) {
    const int col = n0 + wc * (BN / WN) + j * 16 + lr;
    if (col >= NP) continue;
    const bool real = col < Nreal;
    const float bv = real ? bias[col] : 0.f;
    float s = 0.f, q = 0.f;
    #pragma unroll
    for (int i = 0; i < FRAG_M; ++i) {
      #pragma unroll
      for (int r = 0; r < 4; ++r) {
        const int row = row0 + wr * (128 / WM) + i * 16 + lrow + r;
        float v = acc[i][j][r] + bv;
        if (EPI == EPI_RELU) v = fmaxf(v, 0.f);
        if (!real) v = 0.f;
        const unsigned short hv = f2bf(v);
        C[(size_t)row * CS + col] = hv;
        if (EPI == EPI_STATS) {
          const float vr = bf2f(hv);
          s += vr;
          q = fmaf(vr, vr, q);
        }
      }
    }
    if (EPI == EPI_STATS) {
      s += __shfl_xor(s, 16); s += __shfl_xor(s, 32);
      q += __shfl_xor(q, 16); q += __shfl_xor(q, 32);
      if (lane < 16) {
        atomicAdd(&sum[col], s);
        atomicAdd(&sumsq[col], q);
      }
    }
  }
}

// ---------------------------------------------------------------------------
// Mod-einsum GEMM (R11-proven form): R5 LDS structure + bijective XCD swizzle.
__global__ __launch_bounds__(256) void gemm_mod(
    const unsigned short* __restrict__ A,    // out_bf [16384][256]
    const unsigned short* __restrict__ Wt,   // modWt [2048][256]
    const float* __restrict__ bias, unsigned short* __restrict__ C,
    float* __restrict__ sum, float* __restrict__ sumsq)
{
  __shared__ unsigned short As[128 * 32];
  __shared__ unsigned short Bs[128 * 32];
  const int lin = blockIdx.x;
  const int swz = (lin & 7) * 256 + (lin >> 3);
  const int row0 = (swz >> 4) * 128;
  const int n0 = (swz & 15) * 128;
  const int tid = threadIdx.x;
  const int wid = tid >> 6, lane = tid & 63;
  const int wr = wid >> 1, wc = wid & 1;
  const int arow = tid >> 2;
  const int kcol = (tid & 3) * 8;
  const int lr = lane & 15, lk = (lane >> 4) * 8;
  const int lrow = (lane >> 4) * 4;

  f32x4 acc[4][4] = {};
  for (int k0 = 0; k0 < 256; k0 += 32) {
    gload_lds16(A + (size_t)(row0 + arow) * 256 + k0 + kcol, (char*)As + tid * 16);
    gload_lds16(A + (size_t)(row0 + 64 + arow) * 256 + k0 + kcol, (char*)As + 4096 + tid * 16);
    gload_lds16(Wt + (size_t)(n0 + arow) * 256 + k0 + kcol, (char*)Bs + tid * 16);
    gload_lds16(Wt + (size_t)(n0 + 64 + arow) * 256 + k0 + kcol, (char*)Bs + 4096 + tid * 16);
    __syncthreads();
    bf16x8 a[4], b[4];
    #pragma unroll
    for (int i = 0; i < 4; ++i)
      a[i] = *reinterpret_cast<const bf16x8*>(&As[(wr * 64 + i * 16 + lr) * 32 + lk]);
    #pragma unroll
    for (int j = 0; j < 4; ++j)
      b[j] = *reinterpret_cast<const bf16x8*>(&Bs[(wc * 64 + j * 16 + lr) * 32 + lk]);
    #pragma unroll
    for (int i = 0; i < 4; ++i)
      #pragma unroll
      for (int j = 0; j < 4; ++j)
        acc[i][j] = __builtin_amdgcn_mfma_f32_16x16x32_bf16(a[i], b[j], acc[i][j], 0, 0, 0);
    __syncthreads();
  }
  #pragma unroll
  for (int j = 0; j < 4; ++j) {
    const int col = n0 + wc * 64 + j * 16 + lr;
    const float bv = bias[col];
    float s = 0.f, q = 0.f;
    #pragma unroll
    for (int i = 0; i < 4; ++i) {
      #pragma unroll
      for (int r = 0; r < 4; ++r) {
        const int row = row0 + wr * 64 + i * 16 + lrow + r;
        const unsigned short hv = f2bf(acc[i][j][r] + bv);
        C[(size_t)row * 2048 + col] = hv;
        const float vr = bf2f(hv);
        s += vr;
        q = fmaf(vr, vr, q);
      }
    }
    s += __shfl_xor(s, 16); s += __shfl_xor(s, 32);
    q += __shfl_xor(q, 16); q += __shfl_xor(q, 32);
    if (lane < 16) {
      atomicAdd(&sum[col], s);
      atomicAdd(&sumsq[col], q);
    }
  }
}

// ---------------------------------------------------------------------------
// Fused select iteration (R11-proven).
template<bool RELU_A>
__global__ __launch_bounds__(256) void fused_select(
    const unsigned short* __restrict__ A, const unsigned short* __restrict__ selWt,
    const float* __restrict__ selb, const unsigned short* __restrict__ condWt,
    const float* __restrict__ condb, const unsigned short* __restrict__ emb,
    const float* __restrict__ u, int u_off,
    float* __restrict__ gs, unsigned short* __restrict__ siout)
{
  __shared__ unsigned short As[128 * 32];
  __shared__ unsigned short Bs[64 * 32];
  __shared__ unsigned short Ls[128 * 72];
  const int tid = threadIdx.x;
  const int wid = tid >> 6, lane = tid & 63;
  const int lr = lane & 15, hi = lane >> 4;
  const int lk = hi * 8;
  const int row0 = blockIdx.x * 128;
  const int arow = tid >> 2, kcol = (tid & 3) * 8;

  {
    f32x4 acc[2][4] = {};
    for (int k0 = 0; k0 < 256; k0 += 32) {
      gload_lds16(A + (size_t)(row0 + arow) * 256 + k0 + kcol, (char*)As + tid * 16);
      gload_lds16(A + (size_t)(row0 + 64 + arow) * 256 + k0 + kcol, (char*)As + 4096 + tid * 16);
      gload_lds16(selWt + (size_t)arow * 256 + k0 + kcol, (char*)Bs + tid * 16);
      __syncthreads();
      bf16x8 a[2], b[4];
      #pragma unroll
      for (int i = 0; i < 2; ++i) {
        a[i] = *reinterpret_cast<const bf16x8*>(&As[(wid * 32 + i * 16 + lr) * 32 + lk]);
        if (RELU_A) a[i] = relu_bf8(a[i]);
      }
      #pragma unroll
      for (int j = 0; j < 4; ++j)
        b[j] = *reinterpret_cast<const bf16x8*>(&Bs[(j * 16 + lr) * 32 + lk]);
      #pragma unroll
      for (int i = 0; i < 2; ++i)
        #pragma unroll
        for (int j = 0; j < 4; ++j)
          acc[i][j] = __builtin_amdgcn_mfma_f32_16x16x32_bf16(a[i], b[j], acc[i][j], 0, 0, 0);
      __syncthreads();
    }
    #pragma unroll
    for (int j = 0; j < 4; ++j) {
      const int col = j * 16 + lr;
      const float bv = selb[col];
      #pragma unroll
      for (int i = 0; i < 2; ++i)
        #pragma unroll
        for (int r = 0; r < 4; ++r) {
          const int row = wid * 32 + i * 16 + hi * 4 + r;
          Ls[row * 72 + col] = f2bf(tanhf(acc[i][j][r] + bv));
        }
    }
  }
  __syncthreads();

  #pragma unroll
  for (int p = 0; p < 4; ++p) {
    const int pair = p * 256 + tid;
    const int bl = pair >> 3, mm = pair & 7;
    const int bg = row0 + bl;
    float v[8];
    #pragma unroll
    for (int jj = 0; jj < 8; ++jj) v[jj] = bf2f(Ls[bl * 72 + mm * 8 + jj]);
    const float* up = u + (size_t)bg * 192 + u_off + mm * 8;
    #pragma unroll
    for (int jj = 0; jj < 8; ++jj) {
      const float uu = fminf(fmaxf(up[jj], 1e-10f), 0.9999999f);
      v[jj] -= logf(-logf(uu));
    }
    float mx = v[0];
    #pragma unroll
    for (int jj = 1; jj < 8; ++jj) mx = fmaxf(mx, v[jj]);
    float s = 0.f;
    #pragma unroll
    for (int jj = 0; jj < 8; ++jj) { v[jj] = expf(v[jj] - mx); s += v[jj]; }
    const float inv = 1.f / s;
    float* op = gs + (size_t)bg * 64 + mm * 8;
    #pragma unroll
    for (int jj = 0; jj < 8; ++jj) op[jj] = v[jj] * inv;
  }

  {
    const int wr2 = wid >> 1, wc2 = wid & 1;
    f32x4 acc2[4][8] = {};
    #pragma unroll
    for (int kq = 0; kq < 2; ++kq) {
      const int k0 = kq * 32;
      bf16x8 a2[4];
      #pragma unroll
      for (int i = 0; i < 4; ++i)
        a2[i] = *reinterpret_cast<const bf16x8*>(
            &Ls[(wr2 * 64 + i * 16 + lr) * 72 + k0 + hi * 8]);
      #pragma unroll
      for (int j = 0; j < 8; ++j) {
        const bf16x8 b2 = *reinterpret_cast<const bf16x8*>(
            condWt + (size_t)(wc2 * 128 + j * 16 + lr) * 64 + k0 + hi * 8);
        #pragma unroll
        for (int i = 0; i < 4; ++i)
          acc2[i][j] = __builtin_amdgcn_mfma_f32_16x16x32_bf16(a2[i], b2, acc2[i][j], 0, 0, 0);
      }
    }
    #pragma unroll
    for (int j = 0; j < 8; ++j) {
      const int col = wc2 * 128 + j * 16 + lr;
      const float bv = condb[col];
      #pragma unroll
      for (int i = 0; i < 4; ++i)
        #pragma unroll
        for (int r = 0; r < 4; ++r) {
          const int row = row0 + wr2 * 64 + i * 16 + hi * 4 + r;
          float vv = (acc2[i][j][r] + bv) * bf2f(emb[(size_t)row * 256 + col]);
          siout[(size_t)row * 256 + col] = f2bf(fmaxf(vv, 0.f));
        }
    }
  }
}

// ---------------------------------------------------------------------------
// Final select: MFMA GEMM (K=256, N=16 pad, 8 real) + gumbel epilogue.
__global__ __launch_bounds__(256) void gemm_fsel(
    const unsigned short* __restrict__ A, const unsigned short* __restrict__ Wt,
    const float* __restrict__ bias, const float* __restrict__ u,
    float* __restrict__ fs)
{
  __shared__ unsigned short As[128 * 32];
  __shared__ unsigned short Bs[16 * 32];
  const int row0 = blockIdx.y * 128;
  const int tid = threadIdx.x;
  const int wid = tid >> 6, lane = tid & 63;
  const int arow = tid >> 2, kcol = (tid & 3) * 8;
  const int lr = lane & 15, hi = lane >> 4;
  const int lk = hi * 8;

  f32x4 acc[2] = {};
  for (int k0 = 0; k0 < 256; k0 += 32) {
    gload_lds16(A + (size_t)(row0 + arow) * 256 + k0 + kcol, (char*)As + tid * 16);
    gload_lds16(A + (size_t)(row0 + 64 + arow) * 256 + k0 + kcol, (char*)As + 4096 + tid * 16);
    if (wid == 0)
      gload_lds16(Wt + (size_t)(lane >> 2) * 256 + k0 + (lane & 3) * 8, (char*)Bs + lane * 16);
    __syncthreads();
    bf16x8 a[2];
    #pragma unroll
    for (int i = 0; i < 2; ++i)
      a[i] = *reinterpret_cast<const bf16x8*>(&As[(wid * 32 + i * 16 + lr) * 32 + lk]);
    const bf16x8 b = *reinterpret_cast<const bf16x8*>(&Bs[lr * 32 + lk]);
    #pragma unroll
    for (int i = 0; i < 2; ++i)
      acc[i] = __builtin_amdgcn_mfma_f32_16x16x32_bf16(a[i], b, acc[i], 0, 0, 0);
    __syncthreads();
  }
  const float bv = (lr < 8) ? bias[lr] : 0.f;
  #pragma unroll
  for (int i = 0; i < 2; ++i) {
    #pragma unroll
    for (int r = 0; r < 4; ++r) {
      const int row = row0 + wid * 32 + i * 16 + hi * 4 + r;
      float v = acc[i][r] + bv;
      if (lr < 8) {
        const float uu = fminf(fmaxf(u[(size_t)row * 8 + lr], 1e-10f), 0.9999999f);
        v -= logf(-logf(uu));
      }
      float mx = v;
      mx = fmaxf(mx, __shfl_xor(mx, 1));
      mx = fmaxf(mx, __shfl_xor(mx, 2));
      mx = fmaxf(mx, __shfl_xor(mx, 4));
      const float e = expf(v - mx);
      float ssum = e;
      ssum += __shfl_xor(ssum, 1);
      ssum += __shfl_xor(ssum, 2);
      ssum += __shfl_xor(ssum, 4);
      if (lr < 8) fs[(size_t)row * 8 + lr] = e / ssum;
    }
  }
}

// ---------------------------------------------------------------------------
// Fold mod weights with inline bn1 finalize. grid (8, 8, 9).
__global__ __launch_bounds__(256) void fold_modw_all(
    const float* __restrict__ W, const float* __restrict__ g1,
    const float* __restrict__ b1, const float* __restrict__ modb,
    const float* __restrict__ sum1, const float* __restrict__ sumsq1,
    unsigned short* __restrict__ Wt, float* __restrict__ bias2)
{
  const float invB = 1.f / 16384.f;
  if (blockIdx.z == 8) {
    if (blockIdx.y != 0) return;
    const int m = blockIdx.x, h = threadIdx.x;
    float acc = modb[m * 256 + h];
    for (int d = 0; d < 256; ++d) {
      const float mean = sum1[d] * invB;
      const float var = sumsq1[d] * invB - mean * mean;
      const float r = rsqrtf(var + 1e-5f);
      const float c = b1[m * 256 + d] - mean * r * g1[m * 256 + d];
      acc = fmaf(c, W[((size_t)m * 256 + d) * 256 + h], acc);
    }
    bias2[m * 256 + h] = acc;
    return;
  }
  __shared__ float t[32][33];
  const int m = blockIdx.z, d0 = blockIdx.y * 32, h0 = blockIdx.x * 32;
  const int tx = threadIdx.x & 31, ty = threadIdx.x >> 5;
  #pragma unroll
  for (int p = 0; p < 4; ++p) {
    const int d = d0 + ty + p * 8;
    const float mean = sum1[d] * invB;
    const float var = sumsq1[d] * invB - mean * mean;
    const float r = rsqrtf(var + 1e-5f);
    t[ty + p * 8][tx] = W[((size_t)m * 256 + d) * 256 + h0 + tx] * r * g1[m * 256 + d];
  }
  __syncthreads();
  #pragma unroll
  for (int p = 0; p < 4; ++p) {
    const int h = h0 + ty + p * 8;
    Wt[((size_t)m * 256 + h) * 256 + d0 + tx] = f2bf(t[tx][ty + p * 8]);
  }
}

// bn2 finalize.
__global__ void finalize_bn2(const float* __restrict__ sum, const float* __restrict__ sumsq,
                             const float* __restrict__ g, const float* __restrict__ b,
                             float* __restrict__ scale, float* __restrict__ shift)
{
  const int i = blockIdx.x * 256 + threadIdx.x;
  const float invB = 1.f / 16384.f;
  const float m = sum[i] * invB;
  const float v = sumsq[i] * invB - m * m;
  const float r = rsqrtf(v + 1e-5f);
  const float sc = r * g[i];
  scale[i] = sc;
  shift[i] = b[i] - m * sc;
}

// ---------------------------------------------------------------------------
// Fused cascade + last GEMM. Block = 16 samples (4 waves x 4 sequential).
// Cascade output -> LDS ovl[16][264] (bf16); wave 0 runs the 16x18 last GEMM.
// grid 1024.
__global__ __launch_bounds__(256) void cascade_last(
    const unsigned short* __restrict__ H, const float* __restrict__ scale2,
    const float* __restrict__ shift2, const float* __restrict__ gs0,
    const float* __restrict__ gs1, const float* __restrict__ gs2,
    const float* __restrict__ fs, const unsigned short* __restrict__ lastWt,
    const float* __restrict__ lastb, float* __restrict__ out)
{
  __shared__ unsigned short ovl[16 * 264];   // 8.25 KB; row stride 528B (2-way free)
  const int wave = threadIdx.x >> 6, lane = threadIdx.x & 63;
  const int c0 = lane << 2;
  const int base = blockIdx.x * 16;

  for (int s = 0; s < 4; ++s) {
    const int b = __builtin_amdgcn_readfirstlane(base + wave * 4 + s);
    float prev[8][4];
    #pragma unroll
    for (int m = 0; m < 8; ++m) {
      const int gc = m * 256 + c0;
      const ushort4 h = *reinterpret_cast<const ushort4*>(&H[(size_t)b * 2048 + gc]);
      const float4 sc = *reinterpret_cast<const float4*>(&scale2[gc]);
      const float4 sh = *reinterpret_cast<const float4*>(&shift2[gc]);
      prev[m][0] = bf2f(h.x) * sc.x + sh.x;
      prev[m][1] = bf2f(h.y) * sc.y + sh.y;
      prev[m][2] = bf2f(h.z) * sc.z + sh.z;
      prev[m][3] = bf2f(h.w) * sc.w + sh.w;
    }
    const float* sel0 = gs2 + (size_t)b * 64;   // selects[0] = gsels[2]
    const float* sel1 = gs1 + (size_t)b * 64;
    const float* sel2 = gs0 + (size_t)b * 64;
    #pragma unroll
    for (int l = 0; l < 3; ++l) {
      const float* sp = (l == 0) ? sel0 : (l == 1) ? sel1 : sel2;
      float nw[8][4];
      #pragma unroll
      for (int m = 0; m < 8; ++m) {
        float a0 = 0.f, a1 = 0.f, a2 = 0.f, a3 = 0.f;
        #pragma unroll
        for (int k = 0; k < 8; ++k) {
          const float sv = sp[m * 8 + k];    // wave-uniform scalar load
          a0 = fmaf(sv, prev[k][0], a0);
          a1 = fmaf(sv, prev[k][1], a1);
          a2 = fmaf(sv, prev[k][2], a2);
          a3 = fmaf(sv, prev[k][3], a3);
        }
        nw[m][0] = fmaxf(a0, 0.f); nw[m][1] = fmaxf(a1, 0.f);
        nw[m][2] = fmaxf(a2, 0.f); nw[m][3] = fmaxf(a3, 0.f);
      }
      #pragma unroll
      for (int m = 0; m < 8; ++m)
        #pragma unroll
        for (int c = 0; c < 4; ++c)
          prev[m][c] = nw[m][c];
    }
    const float* fp = fs + (size_t)b * 8;
    float ov[4] = {0.f, 0.f, 0.f, 0.f};
    #pragma unroll
    for (int m = 0; m < 8; ++m) {
      const float sv = fp[m];
      ov[0] = fmaf(sv, prev[m][0], ov[0]);
      ov[1] = fmaf(sv, prev[m][1], ov[1]);
      ov[2] = fmaf(sv, prev[m][2], ov[2]);
      ov[3] = fmaf(sv, prev[m][3], ov[3]);
    }
    ushort4 o;
    o.x = f2bf(ov[0]); o.y = f2bf(ov[1]); o.z = f2bf(ov[2]); o.w = f2bf(ov[3]);
    *reinterpret_cast<ushort4*>(&ovl[(wave * 4 + s) * 264 + c0]) = o;
  }
  __syncthreads();

  // wave 0: last GEMM 16x18 over K=256 (2 col fragments, lastWt L2-hot).
  if (wave == 0) {
    const int lr = lane & 15, hi = lane >> 4;
    f32x4 acc[2] = {};
    #pragma unroll
    for (int ks = 0; ks < 8; ++ks) {
      const bf16x8 a = *reinterpret_cast<const bf16x8*>(&ovl[lr * 264 + ks * 32 + hi * 8]);
      #pragma unroll
      for (int j = 0; j < 2; ++j) {
        const bf16x8 b = *reinterpret_cast<const bf16x8*>(
            lastWt + (size_t)(j * 16 + lr) * 256 + ks * 32 + hi * 8);
        acc[j] = __builtin_amdgcn_mfma_f32_16x16x32_bf16(a, b, acc[j], 0, 0, 0);
      }
    }
    #pragma unroll
    for (int j = 0; j < 2; ++j) {
      const int col = j * 16 + lr;
      if (col < 18) {
        const float bv = lastb[col];
        #pragma unroll
        for (int r = 0; r < 4; ++r)
          out[(size_t)(base + hi * 4 + r) * 18 + col] = acc[j][r] + bv;
      }
    }
  }
}

extern "C" void kernel_launch(void* const* d_in, const int* in_sizes, int n_in,
                              void* d_out, int out_size, void* d_ws, size_t ws_size,
                              hipStream_t stream)
{
  (void)in_sizes; (void)n_in; (void)out_size; (void)ws_size;
  const float* x       = (const float*)d_in[0];
  const float* embi    = (const float*)d_in[1];
  const float* u_sel   = (const float*)d_in[2];
  const float* u_fin   = (const float*)d_in[3];
  const float* base_W0 = (const float*)d_in[4];
  const float* base_b0 = (const float*)d_in[5];
  const float* base_W1 = (const float*)d_in[6];
  const float* base_b1 = (const float*)d_in[7];
  const float* em_W0   = (const float*)d_in[8];
  const float* em_b0   = (const float*)d_in[9];
  const float* gat_W0  = (const float*)d_in[10];
  const float* gat_b0  = (const float*)d_in[11];
  const float* gat_W1  = (const float*)d_in[12];
  const float* gat_b1  = (const float*)d_in[13];
  const float* sel_W   = (const float*)d_in[14];
  const float* sel_b   = (const float*)d_in[15];
  const float* selF_W  = (const float*)d_in[16];
  const float* selF_b  = (const float*)d_in[17];
  const float* cond_W  = (const float*)d_in[18];
  const float* cond_b  = (const float*)d_in[19];
  const float* mod_W   = (const float*)d_in[20];
  const float* mod_b   = (const float*)d_in[21];
  const float* last_W  = (const float*)d_in[22];
  const float* last_b  = (const float*)d_in[23];
  const float* bn1_g   = (const float*)d_in[24];
  const float* bn1_b   = (const float*)d_in[25];
  const float* bn2_g   = (const float*)d_in[26];
  const float* bn2_b   = (const float*)d_in[27];

  // --- workspace layout (byte offsets) ---
  char* WSB = (char*)d_ws;
  unsigned short* h_big    = (unsigned short*)(WSB + 0);          // 16384x2048 bf16
  unsigned short* h1e      = (unsigned short*)(WSB + 67108864);   // 16384x416 (em)
  unsigned short* h1       = (unsigned short*)(WSB + 81000448);   // 16384x416 (base)
  unsigned short* emb_bf   = (unsigned short*)(WSB + 103020544);  // 16384x256
  unsigned short* si_bf    = (unsigned short*)(WSB + 111409152);  // 16384x256
  unsigned short* out_bf   = (unsigned short*)(WSB + 119797760);  // 16384x256
  float* gs0   = (float*)(WSB + 130283520);  // 16384x64
  float* gs1   = (float*)(WSB + 134477824);
  float* gs2   = (float*)(WSB + 138672128);
  float* bufFs = (float*)(WSB + 142866432);  // 16384x8
  unsigned short* W0t   = (unsigned short*)(WSB + 143390720);  // 512x128
  unsigned short* emW0t = (unsigned short*)(WSB + 143521792);  // 512x128
  unsigned short* W1t   = (unsigned short*)(WSB + 143652864);  // 256x416
  unsigned short* g0t   = (unsigned short*)(WSB + 143865856);  // 256x416
  unsigned short* g1t   = (unsigned short*)(WSB + 144078848);  // 256x256
  unsigned short* selWt = (unsigned short*)(WSB + 144209920);  // 3x64x256
  unsigned short* condWt= (unsigned short*)(WSB + 144308224);  // 3x256x64
  unsigned short* modWt = (unsigned short*)(WSB + 144406528);  // 8x256x256
  float* bias2  = (float*)(WSB + 146503680);  // 2048
  float* stats  = (float*)(WSB + 146511872);  // 4608 floats
  unsigned short* lastWt = (unsigned short*)(WSB + 146530304); // 64x256 bf16
  float* scale2 = (float*)(WSB + 146563072);  // 2048
  float* shift2 = (float*)(WSB + 146571264);  // 2048
  unsigned short* selFt = (unsigned short*)(WSB + 146579456);  // 16x256 bf16
  float* sum1   = stats;        float* sumsq1 = stats + 256;
  float* sum2   = stats + 512;  float* sumsq2 = stats + 2560;

  const dim3 blk(256);
  // prep (weight transposes + selFt + stats zero)
  prep_all<<<dim3(506), blk, 0, stream>>>(
      base_W0, em_W0, base_W1, gat_W0, gat_W1, sel_W, cond_W, last_W, selF_W,
      W0t, emW0t, W1t, g0t, g1t, selWt, condWt, lastWt, selFt, stats);

  // batched W0 GEMMs from fp32 inputs
  gemm_w0<<<dim3(4, 128, 2), blk, 0, stream>>>(
      x, embi, W0t, emW0t, base_b0, em_b0, h1, h1e);
  // batched mid GEMMs: z=0 W1->out (bn1 stats), z=1 g0->si (relu)
  gemm_mid<<<dim3(4, 128, 2), blk, 0, stream>>>(
      h1, W1t, base_b1, out_bf, h1e, g0t, gat_b0, si_bf, sum1, sumsq1);
  // g1 -> emb
  gemm_bf16<64, 4, 1, EPI_NONE, false><<<dim3(4, 128), blk, 0, stream>>>(
      si_bf, 256, g1t, gat_b1, emb_bf, 256, 256, 256, 256, nullptr, nullptr, nullptr);
  // fused select loop
  fused_select<true><<<dim3(128), blk, 0, stream>>>(
      emb_bf, selWt, sel_b, condWt, cond_b, emb_bf, u_sel, 0, gs0, si_bf);
  fused_select<false><<<dim3(128), blk, 0, stream>>>(
      si_bf, selWt + 16384, sel_b + 64, condWt + 16384, cond_b + 256, emb_bf,
      u_sel, 64, gs1, si_bf);
  fused_select<false><<<dim3(128), blk, 0, stream>>>(
      si_bf, selWt + 32768, sel_b + 128, condWt + 32768, cond_b + 512, emb_bf,
      u_sel, 128, gs2, si_bf);
  // final select (MFMA)
  gemm_fsel<<<dim3(1, 128), blk, 0, stream>>>(si_bf, selFt, selF_b, u_fin, bufFs);
  // bn1 finalize + mod weight fold + bias2
  fold_modw_all<<<dim3(8, 8, 9), blk, 0, stream>>>(
      mod_W, bn1_g, bn1_b, mod_b, sum1, sumsq1, modWt, bias2);
  // mod einsum -> h_big (fused bn2 stats)
  gemm_mod<<<dim3(2048), blk, 0, stream>>>(out_bf, modWt, bias2, h_big, sum2, sumsq2);
  finalize_bn2<<<dim3(8), blk, 0, stream>>>(sum2, sumsq2, bn2_g, bn2_b, scale2, shift2);
  // fused cascade + last GEMM -> d_out
  cascade_last<<<dim3(1024), blk, 0, stream>>>(
      h_big, scale2, shift2, gs0, gs1, gs2, bufFs, lastWt, last_b, (float*)d_out);
}